// Round 3
// baseline (576.672 us; speedup 1.0000x reference)
//
#include <hip/hip_runtime.h>
#include <hip/hip_bf16.h>
#include <cstdint>
#include <cstddef>

// Problem constants
constexpr int HIDDEN = 2048;
constexpr int HEADS  = 16;
constexpr int HD     = 128;       // head dim
constexpr int BATCH  = 2;
constexpr int SEQ    = 2048;
constexpr int MROWS  = BATCH * SEQ;   // 4096 rows for all GEMMs

typedef __attribute__((ext_vector_type(8))) short bf16x8;
typedef __attribute__((ext_vector_type(4))) float f32x4;

__device__ __forceinline__ unsigned short f2bf(float f) {
  union { float f; unsigned int u; } c; c.f = f;
  unsigned int r = c.u + 0x7FFFu + ((c.u >> 16) & 1u);
  return (unsigned short)(r >> 16);
}
__device__ __forceinline__ float bf2f(unsigned short u) {
  union { unsigned int u; float f; } c; c.u = ((unsigned int)u) << 16;
  return c.f;
}

__device__ __forceinline__ void gload_lds16(const void* g, void* l) {
  __builtin_amdgcn_global_load_lds(
      (const __attribute__((address_space(1))) void*)g,
      (__attribute__((address_space(3))) void*)l, 16, 0, 0);
}

// ---------------- fp32 -> bf16 conversion (vectorized float4) ----------------
__global__ void k_cvt(const float* __restrict__ in, unsigned short* __restrict__ out, int n4) {
  int i = blockIdx.x * 256 + threadIdx.x;
  if (i >= n4) return;
  float4 v = reinterpret_cast<const float4*>(in)[i];
  ushort4 o;
  o.x = f2bf(v.x); o.y = f2bf(v.y); o.z = f2bf(v.z); o.w = f2bf(v.w);
  reinterpret_cast<ushort4*>(out)[i] = o;
}

// ---------------- NT GEMM: C[M,N] = A[M,K] * B[N,K]^T, bf16 in, fp32 acc ----
// MODE 0: write bf16 to [B,H,S,D]   (Q, K layout)
// MODE 1: write bf16 to [B,H,D,S]   (V transposed for PV fragment reads)
// MODE 2: write fp32 row-major [M,N] (final output)
template<int MODE>
__global__ __launch_bounds__(256, 2) void k_gemm(const unsigned short* __restrict__ A,
                                                 const unsigned short* __restrict__ Bm,
                                                 void* __restrict__ Cout,
                                                 int M, int N, int K) {
  __shared__ unsigned short As[128 * 32];
  __shared__ unsigned short Bs[128 * 32];
  const int t    = threadIdx.x;
  const int lane = t & 63;
  const int w    = t >> 6;
  const int wr   = w >> 1, wc = w & 1;
  const int m0   = blockIdx.y * 128;
  const int n0   = blockIdx.x * 128;
  const int l15  = lane & 15, lg = lane >> 4;

  f32x4 acc[4][4];
#pragma unroll
  for (int mi = 0; mi < 4; ++mi)
#pragma unroll
    for (int ni = 0; ni < 4; ++ni)
#pragma unroll
      for (int r = 0; r < 4; ++r) acc[mi][ni][r] = 0.f;

  const int rowA = t >> 2;          // 0..63
  const int col8 = (t & 3) * 8;
  const unsigned short* gA0 = A  + (size_t)(m0 + rowA) * K + col8;
  const unsigned short* gA1 = gA0 + (size_t)64 * K;
  const unsigned short* gB0 = Bm + (size_t)(n0 + rowA) * K + col8;
  const unsigned short* gB1 = gB0 + (size_t)64 * K;
  unsigned short* lA0 = As + t * 8;            // byte offset t*16 (linear per wave)
  unsigned short* lA1 = As + 64 * 32 + t * 8;
  unsigned short* lB0 = Bs + t * 8;
  unsigned short* lB1 = Bs + 64 * 32 + t * 8;

  for (int k0 = 0; k0 < K; k0 += 32) {
    gload_lds16(gA0 + k0, lA0);
    gload_lds16(gA1 + k0, lA1);
    gload_lds16(gB0 + k0, lB0);
    gload_lds16(gB1 + k0, lB1);
    __syncthreads();   // compiler emits vmcnt(0) drain before s_barrier

    bf16x8 a[4], b[4];
#pragma unroll
    for (int i = 0; i < 4; ++i)
      a[i] = *reinterpret_cast<const bf16x8*>(&As[(wr * 64 + i * 16 + l15) * 32 + lg * 8]);
#pragma unroll
    for (int i = 0; i < 4; ++i)
      b[i] = *reinterpret_cast<const bf16x8*>(&Bs[(wc * 64 + i * 16 + l15) * 32 + lg * 8]);
#pragma unroll
    for (int mi = 0; mi < 4; ++mi)
#pragma unroll
      for (int ni = 0; ni < 4; ++ni)
        acc[mi][ni] = __builtin_amdgcn_mfma_f32_16x16x32_bf16(a[mi], b[ni], acc[mi][ni], 0, 0, 0);
    __syncthreads();   // protect LDS from next iteration's staging
  }

  // Epilogue.  C/D layout: col = lane&15, row = (lane>>4)*4 + r  [m89-verified]
#pragma unroll
  for (int mi = 0; mi < 4; ++mi) {
#pragma unroll
    for (int ni = 0; ni < 4; ++ni) {
#pragma unroll
      for (int r = 0; r < 4; ++r) {
        int row = m0 + wr * 64 + mi * 16 + lg * 4 + r;   // m index (b*SEQ + s)
        int col = n0 + wc * 64 + ni * 16 + l15;          // n index (h*HD + d)
        float v = acc[mi][ni][r];
        if (MODE == 2) {
          reinterpret_cast<float*>(Cout)[(size_t)row * N + col] = v;
        } else {
          int b = row >> 11, s = row & (SEQ - 1);
          int h = col >> 7, d = col & (HD - 1);
          size_t addr;
          if (MODE == 0) addr = ((size_t)(b * HEADS + h) * SEQ + s) * HD + d;
          else           addr = ((size_t)(b * HEADS + h) * HD + d) * SEQ + s;
          reinterpret_cast<unsigned short*>(Cout)[addr] = f2bf(v);
        }
      }
    }
  }
}

// ---------------- RoPE on Q and K in [B,H,S,D] bf16 layout ----------------
// thread handles 8 (d, d+64) pairs for one (bh, s)
__global__ void k_rope(unsigned short* __restrict__ Qb, unsigned short* __restrict__ Kb) {
  int idx = blockIdx.x * 256 + threadIdx.x;  // 32 * 2048 * 8 = 524288 threads
  int c  = idx & 7;
  int s  = (idx >> 3) & (SEQ - 1);
  int bh = idx >> 14;
  size_t base = ((size_t)bh * SEQ + s) * HD + c * 8;

  bf16x8 ql = *reinterpret_cast<const bf16x8*>(Qb + base);
  bf16x8 qh = *reinterpret_cast<const bf16x8*>(Qb + base + 64);
  bf16x8 kl = *reinterpret_cast<const bf16x8*>(Kb + base);
  bf16x8 kh = *reinterpret_cast<const bf16x8*>(Kb + base + 64);
  bf16x8 qlo, qho, klo, kho;
#pragma unroll
  for (int j = 0; j < 8; ++j) {
    float d   = (float)(c * 8 + j);
    // inv_freq = 10000^(-d/64) = exp(-d * ln(10000)/64)
    float ang = (float)s * expf(d * -0.14391156511756683f);
    float sn, cs;
    __sincosf(ang, &sn, &cs);
    float a0 = bf2f((unsigned short)ql[j]), a1 = bf2f((unsigned short)qh[j]);
    qlo[j] = (short)f2bf(a0 * cs - a1 * sn);
    qho[j] = (short)f2bf(a1 * cs + a0 * sn);
    float b0 = bf2f((unsigned short)kl[j]), b1 = bf2f((unsigned short)kh[j]);
    klo[j] = (short)f2bf(b0 * cs - b1 * sn);
    kho[j] = (short)f2bf(b1 * cs + b0 * sn);
  }
  *reinterpret_cast<bf16x8*>(Qb + base)      = qlo;
  *reinterpret_cast<bf16x8*>(Qb + base + 64) = qho;
  *reinterpret_cast<bf16x8*>(Kb + base)      = klo;
  *reinterpret_cast<bf16x8*>(Kb + base + 64) = kho;
}

// ---------------- causal flash attention (v3) ----------------
// grid (SEQ/128, BATCH*HEADS), 512 threads = 8 waves, each wave owns 16 q-rows.
// v3 changes vs v2:
//  - mirror-flip q-tile for second dispatch half (bh>=16): CU pairs (x, 15-x)
//    -> uniform ~34 KV-iterations per CU instead of worst-case 64.
//  - double-buffered K staging (T3 minimum 2-phase): stage t+1, compute t,
//    single barrier per iteration (compiler's vmcnt(0) drain lands AFTER compute).
//  - V first-half prefetched into registers right after QK^T issue; latency
//    hides under softmax VALU.
constexpr int QB  = 128;   // q rows per block
constexpr int KVB = 64;    // kv rows per iteration
constexpr int NQT = SEQ / QB;   // 16 q-tiles per bh

__global__ __launch_bounds__(512, 4) void k_attn(const unsigned short* __restrict__ Q,
                                                 const unsigned short* __restrict__ Kk,
                                                 const unsigned short* __restrict__ Vt,
                                                 unsigned short* __restrict__ O) {
  __shared__ char lds[2 * 16384 + 16384];   // K dbuf 2x(64x128 bf16, swz) + P 8x(16x64) bf16 (swz)
  char* Ks = lds;
  char* Ps = lds + 2 * 16384;

  const int t    = threadIdx.x;
  const int lane = t & 63;
  const int w    = t >> 6;
  const int l15  = lane & 15, lg = lane >> 4;
  const int bh   = blockIdx.y;
  const int b    = bh >> 4, h = bh & 15;
  // mirror-flip for the second half of the dispatch order: CU gets (x, 15-x)
  const int qt   = (bh >= HEADS) ? (NQT - 1 - (int)blockIdx.x) : (int)blockIdx.x;
  const int q0b  = qt * QB;
  const int q0w  = q0b + w * 16;
  const int qw_hi = q0w + 15;

  const unsigned short* Qb = Q  + (size_t)bh * SEQ * HD;
  const unsigned short* Kb = Kk + (size_t)bh * SEQ * HD;
  const unsigned short* Vb = Vt + (size_t)bh * HD * SEQ;

  // Q fragments hoisted (A-operand: row = lane&15 -> q, k = (lane>>4)*8+i -> d)
  bf16x8 qf[4];
#pragma unroll
  for (int c = 0; c < 4; ++c)
    qf[c] = *reinterpret_cast<const bf16x8*>(Qb + (size_t)(q0w + l15) * HD + c * 32 + lg * 8);

  float mrow[4], lpart[4];
  f32x4 oacc[8];
#pragma unroll
  for (int r = 0; r < 4; ++r) { mrow[r] = -1e30f; lpart[r] = 0.f; }
#pragma unroll
  for (int dt = 0; dt < 8; ++dt)
#pragma unroll
    for (int r = 0; r < 4; ++r) oacc[dt][r] = 0.f;

  // K staging addresses: LDS linear dest, inverse-swizzled global source (rule #21).
  // LDS byte p holds K[row = p>>8][byte (p&255) ^ ((row&7)<<4)]
  const int sp    = t * 16;
  const int srow  = sp >> 8;                            // 0..31 (second gload adds 32)
  const int scolb = (sp & 255) ^ ((srow & 7) << 4);
  const unsigned short* ksrc = Kb + (size_t)srow * HD + (scolb >> 1);
  char* kdst0 = Ks + sp;

  const float scale = 0.08838834764831845f;      // 1/sqrt(128)
  const int nb = q0b / KVB + 2;                  // covers kv <= q0b+127

  // prologue: stage tile 0 into buffer 0
  gload_lds16(ksrc, kdst0);
  gload_lds16(ksrc + (size_t)32 * HD, kdst0 + 8192);
  __syncthreads();

  int cur = 0;
  for (int kb = 0; kb < nb; ++kb) {
    const int kv0 = kb * KVB;
    // prefetch next K tile into the other buffer (overlaps with compute below)
    if (kb + 1 < nb) {
      const size_t goff = (size_t)(kv0 + KVB) * HD;
      char* nd = kdst0 + (cur ^ 1) * 16384;
      gload_lds16(ksrc + goff, nd);
      gload_lds16(ksrc + goff + (size_t)32 * HD, nd + 8192);
    }

    if (kv0 <= qw_hi) {          // wave-uniform causal skip
      const char* Kc = Ks + cur * 16384;
      // ---- QK^T ----
      f32x4 sc[4];
#pragma unroll
      for (int tt = 0; tt < 4; ++tt)
#pragma unroll
        for (int r = 0; r < 4; ++r) sc[tt][r] = 0.f;
#pragma unroll
      for (int tt = 0; tt < 4; ++tt) {
        const int krow = tt * 16 + l15;
        const int xr   = (krow & 7) << 4;
#pragma unroll
        for (int c = 0; c < 4; ++c) {
          bf16x8 kf = *reinterpret_cast<const bf16x8*>(
              Kc + krow * 256 + ((c * 64 + lg * 16) ^ xr));
          sc[tt] = __builtin_amdgcn_mfma_f32_16x16x32_bf16(qf[c], kf, sc[tt], 0, 0, 0);
        }
      }

      // ---- V first-half prefetch (latency hides under softmax VALU) ----
      bf16x8 vp[8];
#pragma unroll
      for (int dt = 0; dt < 8; ++dt)
        vp[dt] = *reinterpret_cast<const bf16x8*>(
            Vb + (size_t)(dt * 16 + l15) * SEQ + kv0 + lg * 8);

      // ---- online softmax (defer-max THR=8, per-lane deferred sums) ----
      const int prow_base = lg * 4;
#pragma unroll
      for (int r = 0; r < 4; ++r) {
        const int qg = q0w + lg * 4 + r;
        float v0 = sc[0][r] * scale, v1 = sc[1][r] * scale;
        float v2 = sc[2][r] * scale, v3 = sc[3][r] * scale;
        if (kv0 +      l15 > qg) v0 = -1e30f;
        if (kv0 + 16 + l15 > qg) v1 = -1e30f;
        if (kv0 + 32 + l15 > qg) v2 = -1e30f;
        if (kv0 + 48 + l15 > qg) v3 = -1e30f;
        float pm = fmaxf(fmaxf(v0, v1), fmaxf(v2, v3));
        pm = fmaxf(pm, __shfl_xor(pm, 1));
        pm = fmaxf(pm, __shfl_xor(pm, 2));
        pm = fmaxf(pm, __shfl_xor(pm, 4));
        pm = fmaxf(pm, __shfl_xor(pm, 8));
        if (__any(pm > mrow[r] + 8.f)) {           // T13 defer-max
          float mn = fmaxf(mrow[r], pm);
          float al = __expf(mrow[r] - mn);
          lpart[r] *= al;
#pragma unroll
          for (int dt = 0; dt < 8; ++dt) oacc[dt][r] *= al;
          mrow[r] = mn;
        }
        float p0 = __expf(v0 - mrow[r]);
        float p1 = __expf(v1 - mrow[r]);
        float p2 = __expf(v2 - mrow[r]);
        float p3 = __expf(v3 - mrow[r]);
        lpart[r] += (p0 + p1) + (p2 + p3);
        // P -> LDS, swizzled (row stride 128B, XOR (row&7)<<4)
        const int prow = prow_base + r;
        const int xpr  = (prow & 7) << 4;
        char* pw = Ps + w * 2048 + prow * 128;
        *reinterpret_cast<unsigned short*>(pw + (((0 * 32) + l15 * 2) ^ xpr)) = f2bf(p0);
        *reinterpret_cast<unsigned short*>(pw + (((1 * 32) + l15 * 2) ^ xpr)) = f2bf(p1);
        *reinterpret_cast<unsigned short*>(pw + (((2 * 32) + l15 * 2) ^ xpr)) = f2bf(p2);
        *reinterpret_cast<unsigned short*>(pw + (((3 * 32) + l15 * 2) ^ xpr)) = f2bf(p3);
      }
      asm volatile("s_waitcnt lgkmcnt(0)" ::: "memory");  // wave-local P visibility

      // ---- PV ----
      const int xq = (l15 & 7) << 4;
      const char* pr = Ps + w * 2048 + l15 * 128;
      bf16x8 pa0 = *reinterpret_cast<const bf16x8*>(pr + ((0  + lg * 16) ^ xq));
      bf16x8 pa1 = *reinterpret_cast<const bf16x8*>(pr + ((64 + lg * 16) ^ xq));
#pragma unroll
      for (int dt = 0; dt < 8; ++dt) {
        bf16x8 vf1 = *reinterpret_cast<const bf16x8*>(
            Vb + (size_t)(dt * 16 + l15) * SEQ + kv0 + 32 + lg * 8);
        oacc[dt] = __builtin_amdgcn_mfma_f32_16x16x32_bf16(pa0, vp[dt], oacc[dt], 0, 0, 0);
        oacc[dt] = __builtin_amdgcn_mfma_f32_16x16x32_bf16(pa1, vf1, oacc[dt], 0, 0, 0);
      }
    }
    __syncthreads();   // auto vmcnt(0) drain lands here, AFTER compute
    cur ^= 1;
  }

  // ---- epilogue: reduce deferred sums across the 16 lanes of each row ----
  float inv[4];
#pragma unroll
  for (int r = 0; r < 4; ++r) {
    float ls = lpart[r];
    ls += __shfl_xor(ls, 1);
    ls += __shfl_xor(ls, 2);
    ls += __shfl_xor(ls, 4);
    ls += __shfl_xor(ls, 8);
    inv[r] = 1.0f / ls;
  }
#pragma unroll
  for (int dt = 0; dt < 8; ++dt) {
#pragma unroll
    for (int r = 0; r < 4; ++r) {
      int qg = q0w + lg * 4 + r;
      int dv = dt * 16 + l15;
      O[((size_t)(b * SEQ + qg) * HEADS + h) * HD + dv] = f2bf(oacc[dt][r] * inv[r]);
    }
  }
}

// ---------------- launch ----------------
extern "C" void kernel_launch(void* const* d_in, const int* in_sizes, int n_in,
                              void* d_out, int out_size, void* d_ws, size_t ws_size,
                              hipStream_t stream) {
  (void)in_sizes; (void)n_in; (void)out_size; (void)ws_size;
  const float* x  = (const float*)d_in[0];
  const float* Wq = (const float*)d_in[1];
  const float* Wk = (const float*)d_in[2];
  const float* Wv = (const float*)d_in[3];
  const float* Wo = (const float*)d_in[4];
  float* out = (float*)d_out;

  // workspace layout (bf16 = ushort).  Total ≈ 112 MB.
  unsigned short* xb  = (unsigned short*)d_ws;
  unsigned short* wqb = xb  + (size_t)MROWS * HIDDEN;
  unsigned short* wkb = wqb + (size_t)HIDDEN * HIDDEN;
  unsigned short* wvb = wkb + (size_t)HIDDEN * HIDDEN;
  unsigned short* wob = wvb + (size_t)HIDDEN * HIDDEN;
  unsigned short* Qb  = wob + (size_t)HIDDEN * HIDDEN;
  unsigned short* Kb  = Qb  + (size_t)MROWS * HIDDEN;
  unsigned short* Vtb = Kb  + (size_t)MROWS * HIDDEN;
  unsigned short* Ob  = Vtb + (size_t)MROWS * HIDDEN;

  int n4x = MROWS * HIDDEN / 4;     // 2,097,152
  int n4w = HIDDEN * HIDDEN / 4;    // 1,048,576
  k_cvt<<<(n4x + 255) / 256, 256, 0, stream>>>(x,  xb,  n4x);
  k_cvt<<<(n4w + 255) / 256, 256, 0, stream>>>(Wq, wqb, n4w);
  k_cvt<<<(n4w + 255) / 256, 256, 0, stream>>>(Wk, wkb, n4w);
  k_cvt<<<(n4w + 255) / 256, 256, 0, stream>>>(Wv, wvb, n4w);
  k_cvt<<<(n4w + 255) / 256, 256, 0, stream>>>(Wo, wob, n4w);

  dim3 gg(HIDDEN / 128, MROWS / 128);   // (16, 32)
  k_gemm<0><<<gg, 256, 0, stream>>>(xb, wqb, Qb,  MROWS, HIDDEN, HIDDEN);
  k_gemm<0><<<gg, 256, 0, stream>>>(xb, wkb, Kb,  MROWS, HIDDEN, HIDDEN);
  k_gemm<1><<<gg, 256, 0, stream>>>(xb, wvb, Vtb, MROWS, HIDDEN, HIDDEN);

  k_rope<<<(BATCH * HEADS * SEQ * 8) / 256, 256, 0, stream>>>(Qb, Kb);

  k_attn<<<dim3(SEQ / QB, BATCH * HEADS), 512, 0, stream>>>(Qb, Kb, Vtb, Ob);

  k_gemm<2><<<gg, 256, 0, stream>>>(Ob, wob, out, MROWS, HIDDEN, HIDDEN);
}

// Round 4
// 418.050 us; speedup vs baseline: 1.3794x; 1.3794x over previous
//
#include <hip/hip_runtime.h>
#include <hip/hip_bf16.h>
#include <cstdint>
#include <cstddef>

// Problem constants
constexpr int HIDDEN = 2048;
constexpr int HEADS  = 16;
constexpr int HD     = 128;       // head dim
constexpr int BATCH  = 2;
constexpr int SEQ    = 2048;
constexpr int MROWS  = BATCH * SEQ;   // 4096 rows for all GEMMs

typedef __attribute__((ext_vector_type(8))) short bf16x8;
typedef __attribute__((ext_vector_type(4))) float f32x4;

__device__ __forceinline__ unsigned short f2bf(float f) {
  union { float f; unsigned int u; } c; c.f = f;
  unsigned int r = c.u + 0x7FFFu + ((c.u >> 16) & 1u);
  return (unsigned short)(r >> 16);
}
__device__ __forceinline__ float bf2f(unsigned short u) {
  union { unsigned int u; float f; } c; c.u = ((unsigned int)u) << 16;
  return c.f;
}

__device__ __forceinline__ void gload_lds16(const void* g, void* l) {
  __builtin_amdgcn_global_load_lds(
      (const __attribute__((address_space(1))) void*)g,
      (__attribute__((address_space(3))) void*)l, 16, 0, 0);
}

// ---------------- fp32 -> bf16 conversion (vectorized float4) ----------------
__global__ void k_cvt(const float* __restrict__ in, unsigned short* __restrict__ out, int n4) {
  int i = blockIdx.x * 256 + threadIdx.x;
  if (i >= n4) return;
  float4 v = reinterpret_cast<const float4*>(in)[i];
  ushort4 o;
  o.x = f2bf(v.x); o.y = f2bf(v.y); o.z = f2bf(v.z); o.w = f2bf(v.w);
  reinterpret_cast<ushort4*>(out)[i] = o;
}

// ---------------- NT GEMM: C[M,N] = A[M,K] * B[N,K]^T, bf16 in, fp32 acc ----
// MODE 0: write bf16 to [B,H,S,D]   (Q, K layout)
// MODE 1: write bf16 to [B,H,D,S]   (V transposed for PV fragment reads)
// MODE 2: write fp32 row-major [M,N] (final output)
template<int MODE>
__global__ __launch_bounds__(256, 2) void k_gemm(const unsigned short* __restrict__ A,
                                                 const unsigned short* __restrict__ Bm,
                                                 void* __restrict__ Cout,
                                                 int M, int N, int K) {
  __shared__ unsigned short As[128 * 32];
  __shared__ unsigned short Bs[128 * 32];
  const int t    = threadIdx.x;
  const int lane = t & 63;
  const int w    = t >> 6;
  const int wr   = w >> 1, wc = w & 1;
  const int m0   = blockIdx.y * 128;
  const int n0   = blockIdx.x * 128;
  const int l15  = lane & 15, lg = lane >> 4;

  f32x4 acc[4][4];
#pragma unroll
  for (int mi = 0; mi < 4; ++mi)
#pragma unroll
    for (int ni = 0; ni < 4; ++ni)
#pragma unroll
      for (int r = 0; r < 4; ++r) acc[mi][ni][r] = 0.f;

  const int rowA = t >> 2;          // 0..63
  const int col8 = (t & 3) * 8;
  const unsigned short* gA0 = A  + (size_t)(m0 + rowA) * K + col8;
  const unsigned short* gA1 = gA0 + (size_t)64 * K;
  const unsigned short* gB0 = Bm + (size_t)(n0 + rowA) * K + col8;
  const unsigned short* gB1 = gB0 + (size_t)64 * K;
  unsigned short* lA0 = As + t * 8;            // byte offset t*16 (linear per wave)
  unsigned short* lA1 = As + 64 * 32 + t * 8;
  unsigned short* lB0 = Bs + t * 8;
  unsigned short* lB1 = Bs + 64 * 32 + t * 8;

  for (int k0 = 0; k0 < K; k0 += 32) {
    gload_lds16(gA0 + k0, lA0);
    gload_lds16(gA1 + k0, lA1);
    gload_lds16(gB0 + k0, lB0);
    gload_lds16(gB1 + k0, lB1);
    __syncthreads();   // compiler emits vmcnt(0) drain before s_barrier

    bf16x8 a[4], b[4];
#pragma unroll
    for (int i = 0; i < 4; ++i)
      a[i] = *reinterpret_cast<const bf16x8*>(&As[(wr * 64 + i * 16 + l15) * 32 + lg * 8]);
#pragma unroll
    for (int i = 0; i < 4; ++i)
      b[i] = *reinterpret_cast<const bf16x8*>(&Bs[(wc * 64 + i * 16 + l15) * 32 + lg * 8]);
#pragma unroll
    for (int mi = 0; mi < 4; ++mi)
#pragma unroll
      for (int ni = 0; ni < 4; ++ni)
        acc[mi][ni] = __builtin_amdgcn_mfma_f32_16x16x32_bf16(a[mi], b[ni], acc[mi][ni], 0, 0, 0);
    __syncthreads();   // protect LDS from next iteration's staging
  }

  // Epilogue.  C/D layout: col = lane&15, row = (lane>>4)*4 + r  [m89-verified]
#pragma unroll
  for (int mi = 0; mi < 4; ++mi) {
#pragma unroll
    for (int ni = 0; ni < 4; ++ni) {
#pragma unroll
      for (int r = 0; r < 4; ++r) {
        int row = m0 + wr * 64 + mi * 16 + lg * 4 + r;   // m index (b*SEQ + s)
        int col = n0 + wc * 64 + ni * 16 + l15;          // n index (h*HD + d)
        float v = acc[mi][ni][r];
        if (MODE == 2) {
          reinterpret_cast<float*>(Cout)[(size_t)row * N + col] = v;
        } else {
          int b = row >> 11, s = row & (SEQ - 1);
          int h = col >> 7, d = col & (HD - 1);
          size_t addr;
          if (MODE == 0) addr = ((size_t)(b * HEADS + h) * SEQ + s) * HD + d;
          else           addr = ((size_t)(b * HEADS + h) * HD + d) * SEQ + s;
          reinterpret_cast<unsigned short*>(Cout)[addr] = f2bf(v);
        }
      }
    }
  }
}

// ---------------- RoPE on Q and K in [B,H,S,D] bf16 layout ----------------
// thread handles 8 (d, d+64) pairs for one (bh, s)
__global__ void k_rope(unsigned short* __restrict__ Qb, unsigned short* __restrict__ Kb) {
  int idx = blockIdx.x * 256 + threadIdx.x;  // 32 * 2048 * 8 = 524288 threads
  int c  = idx & 7;
  int s  = (idx >> 3) & (SEQ - 1);
  int bh = idx >> 14;
  size_t base = ((size_t)bh * SEQ + s) * HD + c * 8;

  bf16x8 ql = *reinterpret_cast<const bf16x8*>(Qb + base);
  bf16x8 qh = *reinterpret_cast<const bf16x8*>(Qb + base + 64);
  bf16x8 kl = *reinterpret_cast<const bf16x8*>(Kb + base);
  bf16x8 kh = *reinterpret_cast<const bf16x8*>(Kb + base + 64);
  bf16x8 qlo, qho, klo, kho;
#pragma unroll
  for (int j = 0; j < 8; ++j) {
    float d   = (float)(c * 8 + j);
    // inv_freq = 10000^(-d/64) = exp(-d * ln(10000)/64)
    float ang = (float)s * expf(d * -0.14391156511756683f);
    float sn, cs;
    __sincosf(ang, &sn, &cs);
    float a0 = bf2f((unsigned short)ql[j]), a1 = bf2f((unsigned short)qh[j]);
    qlo[j] = (short)f2bf(a0 * cs - a1 * sn);
    qho[j] = (short)f2bf(a1 * cs + a0 * sn);
    float b0 = bf2f((unsigned short)kl[j]), b1 = bf2f((unsigned short)kh[j]);
    klo[j] = (short)f2bf(b0 * cs - b1 * sn);
    kho[j] = (short)f2bf(b1 * cs + b0 * sn);
  }
  *reinterpret_cast<bf16x8*>(Qb + base)      = qlo;
  *reinterpret_cast<bf16x8*>(Qb + base + 64) = qho;
  *reinterpret_cast<bf16x8*>(Kb + base)      = klo;
  *reinterpret_cast<bf16x8*>(Kb + base + 64) = kho;
}

// ---------------- causal flash attention (v4) ----------------
// grid (SEQ/128, BATCH*HEADS), 512 threads = 8 waves, each wave owns 16 q-rows.
// v4 vs v3: dropped V register prefetch (spilled at 64-VGPR alloc);
// pinned waves_per_eu(4,4) -> 128-VGPR budget, no scratch spills.
// Kept: mirror-flip balance, double-buffered swizzled K staging.
constexpr int QB  = 128;   // q rows per block
constexpr int KVB = 64;    // kv rows per iteration
constexpr int NQT = SEQ / QB;   // 16 q-tiles per bh

__global__ __launch_bounds__(512)
__attribute__((amdgpu_waves_per_eu(4, 4)))
void k_attn(const unsigned short* __restrict__ Q,
            const unsigned short* __restrict__ Kk,
            const unsigned short* __restrict__ Vt,
            unsigned short* __restrict__ O) {
  __shared__ char lds[2 * 16384 + 16384];   // K dbuf 2x(64x128 bf16, swz) + P 8x(16x64) bf16 (swz)
  char* Ks = lds;
  char* Ps = lds + 2 * 16384;

  const int t    = threadIdx.x;
  const int lane = t & 63;
  const int w    = t >> 6;
  const int l15  = lane & 15, lg = lane >> 4;
  const int bh   = blockIdx.y;
  const int b    = bh >> 4, h = bh & 15;
  // mirror-flip for the second half of the dispatch order: CU gets (x, 15-x)
  const int qt   = (bh >= HEADS) ? (NQT - 1 - (int)blockIdx.x) : (int)blockIdx.x;
  const int q0b  = qt * QB;
  const int q0w  = q0b + w * 16;
  const int qw_hi = q0w + 15;

  const unsigned short* Qb = Q  + (size_t)bh * SEQ * HD;
  const unsigned short* Kb = Kk + (size_t)bh * SEQ * HD;
  const unsigned short* Vb = Vt + (size_t)bh * HD * SEQ;

  // Q fragments hoisted (A-operand: row = lane&15 -> q, k = (lane>>4)*8+i -> d)
  bf16x8 qf[4];
#pragma unroll
  for (int c = 0; c < 4; ++c)
    qf[c] = *reinterpret_cast<const bf16x8*>(Qb + (size_t)(q0w + l15) * HD + c * 32 + lg * 8);

  float mrow[4], lpart[4];
  f32x4 oacc[8];
#pragma unroll
  for (int r = 0; r < 4; ++r) { mrow[r] = -1e30f; lpart[r] = 0.f; }
#pragma unroll
  for (int dt = 0; dt < 8; ++dt)
#pragma unroll
    for (int r = 0; r < 4; ++r) oacc[dt][r] = 0.f;

  // K staging addresses: LDS linear dest, inverse-swizzled global source (rule #21).
  // LDS byte p holds K[row = p>>8][byte (p&255) ^ ((row&7)<<4)]
  const int sp    = t * 16;
  const int srow  = sp >> 8;                            // 0..31 (second gload adds 32)
  const int scolb = (sp & 255) ^ ((srow & 7) << 4);
  const unsigned short* ksrc = Kb + (size_t)srow * HD + (scolb >> 1);
  char* kdst0 = Ks + sp;

  const float scale = 0.08838834764831845f;      // 1/sqrt(128)
  const int nb = q0b / KVB + 2;                  // covers kv <= q0b+127

  // prologue: stage tile 0 into buffer 0
  gload_lds16(ksrc, kdst0);
  gload_lds16(ksrc + (size_t)32 * HD, kdst0 + 8192);
  __syncthreads();

  int cur = 0;
  for (int kb = 0; kb < nb; ++kb) {
    const int kv0 = kb * KVB;
    // prefetch next K tile into the other buffer (overlaps with compute below)
    if (kb + 1 < nb) {
      const size_t goff = (size_t)(kv0 + KVB) * HD;
      char* nd = kdst0 + (cur ^ 1) * 16384;
      gload_lds16(ksrc + goff, nd);
      gload_lds16(ksrc + goff + (size_t)32 * HD, nd + 8192);
    }

    if (kv0 <= qw_hi) {          // wave-uniform causal skip
      const char* Kc = Ks + cur * 16384;
      // ---- QK^T ----
      f32x4 sc[4];
#pragma unroll
      for (int tt = 0; tt < 4; ++tt)
#pragma unroll
        for (int r = 0; r < 4; ++r) sc[tt][r] = 0.f;
#pragma unroll
      for (int tt = 0; tt < 4; ++tt) {
        const int krow = tt * 16 + l15;
        const int xr   = (krow & 7) << 4;
#pragma unroll
        for (int c = 0; c < 4; ++c) {
          bf16x8 kf = *reinterpret_cast<const bf16x8*>(
              Kc + krow * 256 + ((c * 64 + lg * 16) ^ xr));
          sc[tt] = __builtin_amdgcn_mfma_f32_16x16x32_bf16(qf[c], kf, sc[tt], 0, 0, 0);
        }
      }

      // ---- online softmax (defer-max THR=8, per-lane deferred sums) ----
      const int prow_base = lg * 4;
#pragma unroll
      for (int r = 0; r < 4; ++r) {
        const int qg = q0w + lg * 4 + r;
        float v0 = sc[0][r] * scale, v1 = sc[1][r] * scale;
        float v2 = sc[2][r] * scale, v3 = sc[3][r] * scale;
        if (kv0 +      l15 > qg) v0 = -1e30f;
        if (kv0 + 16 + l15 > qg) v1 = -1e30f;
        if (kv0 + 32 + l15 > qg) v2 = -1e30f;
        if (kv0 + 48 + l15 > qg) v3 = -1e30f;
        float pm = fmaxf(fmaxf(v0, v1), fmaxf(v2, v3));
        pm = fmaxf(pm, __shfl_xor(pm, 1));
        pm = fmaxf(pm, __shfl_xor(pm, 2));
        pm = fmaxf(pm, __shfl_xor(pm, 4));
        pm = fmaxf(pm, __shfl_xor(pm, 8));
        if (__any(pm > mrow[r] + 8.f)) {           // T13 defer-max
          float mn = fmaxf(mrow[r], pm);
          float al = __expf(mrow[r] - mn);
          lpart[r] *= al;
#pragma unroll
          for (int dt = 0; dt < 8; ++dt) oacc[dt][r] *= al;
          mrow[r] = mn;
        }
        float p0 = __expf(v0 - mrow[r]);
        float p1 = __expf(v1 - mrow[r]);
        float p2 = __expf(v2 - mrow[r]);
        float p3 = __expf(v3 - mrow[r]);
        lpart[r] += (p0 + p1) + (p2 + p3);
        // P -> LDS, swizzled (row stride 128B, XOR (row&7)<<4)
        const int prow = prow_base + r;
        const int xpr  = (prow & 7) << 4;
        char* pw = Ps + w * 2048 + prow * 128;
        *reinterpret_cast<unsigned short*>(pw + (((0 * 32) + l15 * 2) ^ xpr)) = f2bf(p0);
        *reinterpret_cast<unsigned short*>(pw + (((1 * 32) + l15 * 2) ^ xpr)) = f2bf(p1);
        *reinterpret_cast<unsigned short*>(pw + (((2 * 32) + l15 * 2) ^ xpr)) = f2bf(p2);
        *reinterpret_cast<unsigned short*>(pw + (((3 * 32) + l15 * 2) ^ xpr)) = f2bf(p3);
      }
      asm volatile("s_waitcnt lgkmcnt(0)" ::: "memory");  // wave-local P visibility

      // ---- PV ----
      const int xq = (l15 & 7) << 4;
      const char* pr = Ps + w * 2048 + l15 * 128;
      bf16x8 pa0 = *reinterpret_cast<const bf16x8*>(pr + ((0  + lg * 16) ^ xq));
      bf16x8 pa1 = *reinterpret_cast<const bf16x8*>(pr + ((64 + lg * 16) ^ xq));
#pragma unroll
      for (int dt = 0; dt < 8; ++dt) {
        const unsigned short* vrow = Vb + (size_t)(dt * 16 + l15) * SEQ + kv0 + lg * 8;
        bf16x8 vf0 = *reinterpret_cast<const bf16x8*>(vrow);
        bf16x8 vf1 = *reinterpret_cast<const bf16x8*>(vrow + 32);
        oacc[dt] = __builtin_amdgcn_mfma_f32_16x16x32_bf16(pa0, vf0, oacc[dt], 0, 0, 0);
        oacc[dt] = __builtin_amdgcn_mfma_f32_16x16x32_bf16(pa1, vf1, oacc[dt], 0, 0, 0);
      }
    }
    __syncthreads();   // auto vmcnt(0) drain lands here, AFTER compute
    cur ^= 1;
  }

  // ---- epilogue: reduce deferred sums across the 16 lanes of each row ----
  float inv[4];
#pragma unroll
  for (int r = 0; r < 4; ++r) {
    float ls = lpart[r];
    ls += __shfl_xor(ls, 1);
    ls += __shfl_xor(ls, 2);
    ls += __shfl_xor(ls, 4);
    ls += __shfl_xor(ls, 8);
    inv[r] = 1.0f / ls;
  }
#pragma unroll
  for (int dt = 0; dt < 8; ++dt) {
#pragma unroll
    for (int r = 0; r < 4; ++r) {
      int qg = q0w + lg * 4 + r;
      int dv = dt * 16 + l15;
      O[((size_t)(b * SEQ + qg) * HEADS + h) * HD + dv] = f2bf(oacc[dt][r] * inv[r]);
    }
  }
}

// ---------------- launch ----------------
extern "C" void kernel_launch(void* const* d_in, const int* in_sizes, int n_in,
                              void* d_out, int out_size, void* d_ws, size_t ws_size,
                              hipStream_t stream) {
  (void)in_sizes; (void)n_in; (void)out_size; (void)ws_size;
  const float* x  = (const float*)d_in[0];
  const float* Wq = (const float*)d_in[1];
  const float* Wk = (const float*)d_in[2];
  const float* Wv = (const float*)d_in[3];
  const float* Wo = (const float*)d_in[4];
  float* out = (float*)d_out;

  // workspace layout (bf16 = ushort).  Total ≈ 112 MB.
  unsigned short* xb  = (unsigned short*)d_ws;
  unsigned short* wqb = xb  + (size_t)MROWS * HIDDEN;
  unsigned short* wkb = wqb + (size_t)HIDDEN * HIDDEN;
  unsigned short* wvb = wkb + (size_t)HIDDEN * HIDDEN;
  unsigned short* wob = wvb + (size_t)HIDDEN * HIDDEN;
  unsigned short* Qb  = wob + (size_t)HIDDEN * HIDDEN;
  unsigned short* Kb  = Qb  + (size_t)MROWS * HIDDEN;
  unsigned short* Vtb = Kb  + (size_t)MROWS * HIDDEN;
  unsigned short* Ob  = Vtb + (size_t)MROWS * HIDDEN;

  int n4x = MROWS * HIDDEN / 4;     // 2,097,152
  int n4w = HIDDEN * HIDDEN / 4;    // 1,048,576
  k_cvt<<<(n4x + 255) / 256, 256, 0, stream>>>(x,  xb,  n4x);
  k_cvt<<<(n4w + 255) / 256, 256, 0, stream>>>(Wq, wqb, n4w);
  k_cvt<<<(n4w + 255) / 256, 256, 0, stream>>>(Wk, wkb, n4w);
  k_cvt<<<(n4w + 255) / 256, 256, 0, stream>>>(Wv, wvb, n4w);
  k_cvt<<<(n4w + 255) / 256, 256, 0, stream>>>(Wo, wob, n4w);

  dim3 gg(HIDDEN / 128, MROWS / 128);   // (16, 32)
  k_gemm<0><<<gg, 256, 0, stream>>>(xb, wqb, Qb,  MROWS, HIDDEN, HIDDEN);
  k_gemm<0><<<gg, 256, 0, stream>>>(xb, wkb, Kb,  MROWS, HIDDEN, HIDDEN);
  k_gemm<1><<<gg, 256, 0, stream>>>(xb, wvb, Vtb, MROWS, HIDDEN, HIDDEN);

  k_rope<<<(BATCH * HEADS * SEQ * 8) / 256, 256, 0, stream>>>(Qb, Kb);

  k_attn<<<dim3(SEQ / QB, BATCH * HEADS), 512, 0, stream>>>(Qb, Kb, Vtb, Ob);

  k_gemm<2><<<gg, 256, 0, stream>>>(Ob, wob, out, MROWS, HIDDEN, HIDDEN);
}

// Round 5
// 301.289 us; speedup vs baseline: 1.9140x; 1.3875x over previous
//
#include <hip/hip_runtime.h>
#include <hip/hip_bf16.h>
#include <cstdint>
#include <cstddef>

// Problem constants
constexpr int HIDDEN = 2048;
constexpr int HEADS  = 16;
constexpr int HD     = 128;       // head dim
constexpr int BATCH  = 2;
constexpr int SEQ    = 2048;
constexpr int MROWS  = BATCH * SEQ;   // 4096 rows for all GEMMs

typedef __attribute__((ext_vector_type(8))) short bf16x8;
typedef __attribute__((ext_vector_type(4))) float f32x4;

__device__ __forceinline__ unsigned short f2bf(float f) {
  union { float f; unsigned int u; } c; c.f = f;
  unsigned int r = c.u + 0x7FFFu + ((c.u >> 16) & 1u);
  return (unsigned short)(r >> 16);
}
__device__ __forceinline__ float bf2f(unsigned short u) {
  union { unsigned int u; float f; } c; c.u = ((unsigned int)u) << 16;
  return c.f;
}

__device__ __forceinline__ void gload_lds16(const void* g, void* l) {
  __builtin_amdgcn_global_load_lds(
      (const __attribute__((address_space(1))) void*)g,
      (__attribute__((address_space(3))) void*)l, 16, 0, 0);
}

// ---------------- fp32 -> bf16 conversion (vectorized float4) ----------------
__global__ void k_cvt(const float* __restrict__ in, unsigned short* __restrict__ out, int n4) {
  int i = blockIdx.x * 256 + threadIdx.x;
  if (i >= n4) return;
  float4 v = reinterpret_cast<const float4*>(in)[i];
  ushort4 o;
  o.x = f2bf(v.x); o.y = f2bf(v.y); o.z = f2bf(v.z); o.w = f2bf(v.w);
  reinterpret_cast<ushort4*>(out)[i] = o;
}

// ---------------- NT GEMM: C[M,N] = A[M,K] * B[N,K]^T, bf16 in, fp32 acc ----
// MODE 0: write bf16 to [B,H,S,D]   (Q, K layout)
// MODE 1: write bf16 to [B,H,D,S]   (V transposed for PV fragment reads)
// MODE 2: write fp32 row-major [M,N] (final output)
template<int MODE>
__global__ __launch_bounds__(256, 2) void k_gemm(const unsigned short* __restrict__ A,
                                                 const unsigned short* __restrict__ Bm,
                                                 void* __restrict__ Cout,
                                                 int M, int N, int K) {
  __shared__ unsigned short As[128 * 32];
  __shared__ unsigned short Bs[128 * 32];
  const int t    = threadIdx.x;
  const int lane = t & 63;
  const int w    = t >> 6;
  const int wr   = w >> 1, wc = w & 1;
  const int m0   = blockIdx.y * 128;
  const int n0   = blockIdx.x * 128;
  const int l15  = lane & 15, lg = lane >> 4;

  f32x4 acc[4][4];
#pragma unroll
  for (int mi = 0; mi < 4; ++mi)
#pragma unroll
    for (int ni = 0; ni < 4; ++ni)
#pragma unroll
      for (int r = 0; r < 4; ++r) acc[mi][ni][r] = 0.f;

  const int rowA = t >> 2;          // 0..63
  const int col8 = (t & 3) * 8;
  const unsigned short* gA0 = A  + (size_t)(m0 + rowA) * K + col8;
  const unsigned short* gA1 = gA0 + (size_t)64 * K;
  const unsigned short* gB0 = Bm + (size_t)(n0 + rowA) * K + col8;
  const unsigned short* gB1 = gB0 + (size_t)64 * K;
  unsigned short* lA0 = As + t * 8;            // byte offset t*16 (linear per wave)
  unsigned short* lA1 = As + 64 * 32 + t * 8;
  unsigned short* lB0 = Bs + t * 8;
  unsigned short* lB1 = Bs + 64 * 32 + t * 8;

  for (int k0 = 0; k0 < K; k0 += 32) {
    gload_lds16(gA0 + k0, lA0);
    gload_lds16(gA1 + k0, lA1);
    gload_lds16(gB0 + k0, lB0);
    gload_lds16(gB1 + k0, lB1);
    __syncthreads();   // compiler emits vmcnt(0) drain before s_barrier

    bf16x8 a[4], b[4];
#pragma unroll
    for (int i = 0; i < 4; ++i)
      a[i] = *reinterpret_cast<const bf16x8*>(&As[(wr * 64 + i * 16 + l15) * 32 + lg * 8]);
#pragma unroll
    for (int i = 0; i < 4; ++i)
      b[i] = *reinterpret_cast<const bf16x8*>(&Bs[(wc * 64 + i * 16 + l15) * 32 + lg * 8]);
#pragma unroll
    for (int mi = 0; mi < 4; ++mi)
#pragma unroll
      for (int ni = 0; ni < 4; ++ni)
        acc[mi][ni] = __builtin_amdgcn_mfma_f32_16x16x32_bf16(a[mi], b[ni], acc[mi][ni], 0, 0, 0);
    __syncthreads();   // protect LDS from next iteration's staging
  }

  // Epilogue.  C/D layout: col = lane&15, row = (lane>>4)*4 + r  [m89-verified]
#pragma unroll
  for (int mi = 0; mi < 4; ++mi) {
#pragma unroll
    for (int ni = 0; ni < 4; ++ni) {
#pragma unroll
      for (int r = 0; r < 4; ++r) {
        int row = m0 + wr * 64 + mi * 16 + lg * 4 + r;   // m index (b*SEQ + s)
        int col = n0 + wc * 64 + ni * 16 + l15;          // n index (h*HD + d)
        float v = acc[mi][ni][r];
        if (MODE == 2) {
          reinterpret_cast<float*>(Cout)[(size_t)row * N + col] = v;
        } else {
          int b = row >> 11, s = row & (SEQ - 1);
          int h = col >> 7, d = col & (HD - 1);
          size_t addr;
          if (MODE == 0) addr = ((size_t)(b * HEADS + h) * SEQ + s) * HD + d;
          else           addr = ((size_t)(b * HEADS + h) * HD + d) * SEQ + s;
          reinterpret_cast<unsigned short*>(Cout)[addr] = f2bf(v);
        }
      }
    }
  }
}

// ---------------- RoPE on Q and K in [B,H,S,D] bf16 layout ----------------
// thread handles 8 (d, d+64) pairs for one (bh, s)
__global__ void k_rope(unsigned short* __restrict__ Qb, unsigned short* __restrict__ Kb) {
  int idx = blockIdx.x * 256 + threadIdx.x;  // 32 * 2048 * 8 = 524288 threads
  int c  = idx & 7;
  int s  = (idx >> 3) & (SEQ - 1);
  int bh = idx >> 14;
  size_t base = ((size_t)bh * SEQ + s) * HD + c * 8;

  bf16x8 ql = *reinterpret_cast<const bf16x8*>(Qb + base);
  bf16x8 qh = *reinterpret_cast<const bf16x8*>(Qb + base + 64);
  bf16x8 kl = *reinterpret_cast<const bf16x8*>(Kb + base);
  bf16x8 kh = *reinterpret_cast<const bf16x8*>(Kb + base + 64);
  bf16x8 qlo, qho, klo, kho;
#pragma unroll
  for (int j = 0; j < 8; ++j) {
    float d   = (float)(c * 8 + j);
    // inv_freq = 10000^(-d/64) = exp(-d * ln(10000)/64)
    float ang = (float)s * expf(d * -0.14391156511756683f);
    float sn, cs;
    __sincosf(ang, &sn, &cs);
    float a0 = bf2f((unsigned short)ql[j]), a1 = bf2f((unsigned short)qh[j]);
    qlo[j] = (short)f2bf(a0 * cs - a1 * sn);
    qho[j] = (short)f2bf(a1 * cs + a0 * sn);
    float b0 = bf2f((unsigned short)kl[j]), b1 = bf2f((unsigned short)kh[j]);
    klo[j] = (short)f2bf(b0 * cs - b1 * sn);
    kho[j] = (short)f2bf(b1 * cs + b0 * sn);
  }
  *reinterpret_cast<bf16x8*>(Qb + base)      = qlo;
  *reinterpret_cast<bf16x8*>(Qb + base + 64) = qho;
  *reinterpret_cast<bf16x8*>(Kb + base)      = klo;
  *reinterpret_cast<bf16x8*>(Kb + base + 64) = kho;
}

// ---------------- causal flash attention (v5) ----------------
// grid (SEQ/128, BATCH*HEADS), 512 threads = 8 waves, each wave owns 16 q-rows.
// v5 vs v4:
//  - __any-gated defer-max: NO cross-lane shuffle on the common softmax path;
//    full 16-lane max reduce only when the running max grows by >8 (rare).
//  - V staged in LDS (dbuf, XOR-swizzled) shared by all 8 waves: 8x less V
//    read traffic, PV operands from conflict-free LDS instead of global.
//  - mask VALU skipped on fully-unmasked tiles (kv0+63 <= q0w).
// Kept: mirror-flip balance, double-buffered swizzled K staging.
constexpr int QB  = 128;   // q rows per block
constexpr int KVB = 64;    // kv rows per iteration
constexpr int NQT = SEQ / QB;   // 16 q-tiles per bh

__global__ __launch_bounds__(512)
__attribute__((amdgpu_waves_per_eu(4, 4)))
void k_attn(const unsigned short* __restrict__ Q,
            const unsigned short* __restrict__ Kk,
            const unsigned short* __restrict__ Vt,
            unsigned short* __restrict__ O) {
  // K dbuf 2x16K (64 rows x 128B, swz) + V dbuf 2x16K (128 rows x 128B, swz)
  // + P 8 x 2K (16 rows x 128B, swz)  = 80 KB -> 2 blocks/CU
  __shared__ char lds[2 * 16384 + 2 * 16384 + 16384];
  char* Ks = lds;
  char* Vs = lds + 2 * 16384;
  char* Ps = lds + 4 * 16384;

  const int t    = threadIdx.x;
  const int lane = t & 63;
  const int w    = t >> 6;
  const int l15  = lane & 15, lg = lane >> 4;
  const int bh   = blockIdx.y;
  const int b    = bh >> 4, h = bh & 15;
  // mirror-flip for the second half of the dispatch order: CU gets (x, 15-x)
  const int qt   = (bh >= HEADS) ? (NQT - 1 - (int)blockIdx.x) : (int)blockIdx.x;
  const int q0b  = qt * QB;
  const int q0w  = q0b + w * 16;
  const int qw_hi = q0w + 15;

  const unsigned short* Qb = Q  + (size_t)bh * SEQ * HD;
  const unsigned short* Kb = Kk + (size_t)bh * SEQ * HD;
  const unsigned short* Vb = Vt + (size_t)bh * HD * SEQ;

  // Q fragments hoisted (A-operand: row = lane&15 -> q, k = (lane>>4)*8+i -> d)
  bf16x8 qf[4];
#pragma unroll
  for (int c = 0; c < 4; ++c)
    qf[c] = *reinterpret_cast<const bf16x8*>(Qb + (size_t)(q0w + l15) * HD + c * 32 + lg * 8);

  float mrow[4], lpart[4];
  f32x4 oacc[8];
#pragma unroll
  for (int r = 0; r < 4; ++r) { mrow[r] = -1e30f; lpart[r] = 0.f; }
#pragma unroll
  for (int dt = 0; dt < 8; ++dt)
#pragma unroll
    for (int r = 0; r < 4; ++r) oacc[dt][r] = 0.f;

  // K staging: LDS linear dest, inverse-swizzled global source (rule #21).
  // K LDS byte p holds K[row = p>>8 (2 rows/256B... row stride 128B: p>>7)] —
  // layout: row = p>>7 within 64-row tile, byte (p&127) ^ ((row&7)<<4).
  // Each thread stages 16B; 512 threads cover 8 KB (32 rows), two gloads/tile.
  {
  }
  const int krow  = t >> 3;                              // 0..63
  const int kcolb = ((t & 7) << 4) ^ ((krow & 7) << 4);
  const unsigned short* ksrc = Kb + (size_t)krow * HD + (kcolb >> 1);
  char* kdst = Ks + t * 16;                              // covers 8KB; +8192 for rows 64.. n/a (64 rows = 8KB*? )

  // NOTE: 64 rows x 128B = 8 KB per K tile?  No: 64 rows x 128 B = 8192 B.
  // 512 threads x 16 B = 8192 B -> ONE gload per K tile.  (HD=128 -> row=256B!)
  // Correction: K row = 128 elements * 2B = 256B.  Redo with 256B rows:
  // K LDS tile = 64 rows x 256B = 16 KB; thread stages 16B at p = t*16 (8KB half)
  // row = p>>8, byte (p&255) ^ ((row&7)<<4); two gloads cover rows 0..31, 32..63.
  const int sp     = t * 16;
  const int srow   = sp >> 8;
  const int scolb  = (sp & 255) ^ ((srow & 7) << 4);
  const unsigned short* ksrc2 = Kb + (size_t)srow * HD + (scolb >> 1);
  char* kdst2 = Ks + sp;
  (void)krow; (void)kcolb; (void)ksrc; (void)kdst;

  // V staging: V tile in LDS = [dv 0..127] rows x 64 kv * 2B = 128B rows, 16 KB.
  // thread stages 16B at p = t*16 (8 KB = rows 0..63); row = p>>7,
  // byte (p&127) ^ ((row&7)<<4).  Source: Vt[dv][kv] rows of length SEQ.
  const int vrow  = t >> 3;                              // 0..63
  const int vcolb = ((t & 7) << 4) ^ ((vrow & 7) << 4);
  const unsigned short* vsrc = Vb + (size_t)vrow * SEQ + (vcolb >> 1);
  char* vdst = Vs + t * 16;

  const float scale = 0.08838834764831845f;      // 1/sqrt(128)
  const int nb = q0b / KVB + 2;                  // covers kv <= q0b+127

  // prologue: stage K,V tile 0 into buffer 0
  gload_lds16(ksrc2, kdst2);
  gload_lds16(ksrc2 + (size_t)32 * HD, kdst2 + 8192);
  gload_lds16(vsrc, vdst);
  gload_lds16(vsrc + (size_t)64 * SEQ, vdst + 8192);
  __syncthreads();

  int cur = 0;
  for (int kb = 0; kb < nb; ++kb) {
    const int kv0 = kb * KVB;
    // prefetch next K,V tile into the other buffer (overlaps with compute below)
    if (kb + 1 < nb) {
      const int nxt = kv0 + KVB;
      char* nk = kdst2 + (cur ^ 1) * 16384;
      char* nv = vdst  + (cur ^ 1) * 16384;
      gload_lds16(ksrc2 + (size_t)nxt * HD, nk);
      gload_lds16(ksrc2 + (size_t)(nxt + 32) * HD, nk + 8192);
      gload_lds16(vsrc + nxt, nv);
      gload_lds16(vsrc + (size_t)64 * SEQ + nxt, nv + 8192);
    }

    if (kv0 <= qw_hi) {          // wave-uniform causal skip
      const char* Kc = Ks + cur * 16384;
      const char* Vc = Vs + cur * 16384;
      // ---- QK^T ----
      f32x4 sc[4];
#pragma unroll
      for (int tt = 0; tt < 4; ++tt)
#pragma unroll
        for (int r = 0; r < 4; ++r) sc[tt][r] = 0.f;
#pragma unroll
      for (int tt = 0; tt < 4; ++tt) {
        const int kr = tt * 16 + l15;
        const int xr = (kr & 7) << 4;
#pragma unroll
        for (int c = 0; c < 4; ++c) {
          bf16x8 kf = *reinterpret_cast<const bf16x8*>(
              Kc + kr * 256 + ((c * 64 + lg * 16) ^ xr));
          sc[tt] = __builtin_amdgcn_mfma_f32_16x16x32_bf16(qf[c], kf, sc[tt], 0, 0, 0);
        }
      }

      // ---- online softmax: __any-gated defer-max, no common-path cross-lane ----
      const bool full = (kv0 + KVB - 1 <= q0w);   // tile fully unmasked for this wave
#pragma unroll
      for (int r = 0; r < 4; ++r) {
        const int qg = q0w + lg * 4 + r;
        float v0 = sc[0][r] * scale, v1 = sc[1][r] * scale;
        float v2 = sc[2][r] * scale, v3 = sc[3][r] * scale;
        if (!full) {
          if (kv0 +      l15 > qg) v0 = -1e30f;
          if (kv0 + 16 + l15 > qg) v1 = -1e30f;
          if (kv0 + 32 + l15 > qg) v2 = -1e30f;
          if (kv0 + 48 + l15 > qg) v3 = -1e30f;
        }
        float pm = fmaxf(fmaxf(v0, v1), fmaxf(v2, v3));   // per-lane only
        if (__any(pm > mrow[r] + 8.f)) {                  // rare: true max reduce
          float pmr = pm;
          pmr = fmaxf(pmr, __shfl_xor(pmr, 1));
          pmr = fmaxf(pmr, __shfl_xor(pmr, 2));
          pmr = fmaxf(pmr, __shfl_xor(pmr, 4));
          pmr = fmaxf(pmr, __shfl_xor(pmr, 8));
          float mn = fmaxf(mrow[r], pmr);
          float al = __expf(mrow[r] - mn);
          lpart[r] *= al;
#pragma unroll
          for (int dt = 0; dt < 8; ++dt) oacc[dt][r] *= al;
          mrow[r] = mn;
        }
        float p0 = __expf(v0 - mrow[r]);
        float p1 = __expf(v1 - mrow[r]);
        float p2 = __expf(v2 - mrow[r]);
        float p3 = __expf(v3 - mrow[r]);
        lpart[r] += (p0 + p1) + (p2 + p3);
        // P -> LDS, swizzled (row stride 128B, XOR (row&7)<<4)
        const int prow = lg * 4 + r;
        const int xpr  = (prow & 7) << 4;
        char* pw = Ps + w * 2048 + prow * 128;
        *reinterpret_cast<unsigned short*>(pw + (((0 * 32) + l15 * 2) ^ xpr)) = f2bf(p0);
        *reinterpret_cast<unsigned short*>(pw + (((1 * 32) + l15 * 2) ^ xpr)) = f2bf(p1);
        *reinterpret_cast<unsigned short*>(pw + (((2 * 32) + l15 * 2) ^ xpr)) = f2bf(p2);
        *reinterpret_cast<unsigned short*>(pw + (((3 * 32) + l15 * 2) ^ xpr)) = f2bf(p3);
      }
      asm volatile("s_waitcnt lgkmcnt(0)" ::: "memory");  // wave-local P visibility

      // ---- PV (V from swizzled LDS) ----
      const int xq = (l15 & 7) << 4;
      const char* pr = Ps + w * 2048 + l15 * 128;
      bf16x8 pa0 = *reinterpret_cast<const bf16x8*>(pr + ((0  + lg * 16) ^ xq));
      bf16x8 pa1 = *reinterpret_cast<const bf16x8*>(pr + ((64 + lg * 16) ^ xq));
      const int xv = (l15 & 7) << 4;
#pragma unroll
      for (int dt = 0; dt < 8; ++dt) {
        const char* vrl = Vc + (dt * 16 + l15) * 128;
        bf16x8 vf0 = *reinterpret_cast<const bf16x8*>(vrl + ((lg * 16) ^ xv));
        bf16x8 vf1 = *reinterpret_cast<const bf16x8*>(vrl + ((64 + lg * 16) ^ xv));
        oacc[dt] = __builtin_amdgcn_mfma_f32_16x16x32_bf16(pa0, vf0, oacc[dt], 0, 0, 0);
        oacc[dt] = __builtin_amdgcn_mfma_f32_16x16x32_bf16(pa1, vf1, oacc[dt], 0, 0, 0);
      }
    }
    __syncthreads();   // auto vmcnt(0) drain lands here, AFTER compute
    cur ^= 1;
  }

  // ---- epilogue: reduce deferred sums across the 16 lanes of each row ----
  float inv[4];
#pragma unroll
  for (int r = 0; r < 4; ++r) {
    float ls = lpart[r];
    ls += __shfl_xor(ls, 1);
    ls += __shfl_xor(ls, 2);
    ls += __shfl_xor(ls, 4);
    ls += __shfl_xor(ls, 8);
    inv[r] = 1.0f / ls;
  }
#pragma unroll
  for (int dt = 0; dt < 8; ++dt) {
#pragma unroll
    for (int r = 0; r < 4; ++r) {
      int qg = q0w + lg * 4 + r;
      int dv = dt * 16 + l15;
      O[((size_t)(b * SEQ + qg) * HEADS + h) * HD + dv] = f2bf(oacc[dt][r] * inv[r]);
    }
  }
}

// ---------------- launch ----------------
extern "C" void kernel_launch(void* const* d_in, const int* in_sizes, int n_in,
                              void* d_out, int out_size, void* d_ws, size_t ws_size,
                              hipStream_t stream) {
  (void)in_sizes; (void)n_in; (void)out_size; (void)ws_size;
  const float* x  = (const float*)d_in[0];
  const float* Wq = (const float*)d_in[1];
  const float* Wk = (const float*)d_in[2];
  const float* Wv = (const float*)d_in[3];
  const float* Wo = (const float*)d_in[4];
  float* out = (float*)d_out;

  // workspace layout (bf16 = ushort).  Total ≈ 112 MB.
  unsigned short* xb  = (unsigned short*)d_ws;
  unsigned short* wqb = xb  + (size_t)MROWS * HIDDEN;
  unsigned short* wkb = wqb + (size_t)HIDDEN * HIDDEN;
  unsigned short* wvb = wkb + (size_t)HIDDEN * HIDDEN;
  unsigned short* wob = wvb + (size_t)HIDDEN * HIDDEN;
  unsigned short* Qb  = wob + (size_t)HIDDEN * HIDDEN;
  unsigned short* Kb  = Qb  + (size_t)MROWS * HIDDEN;
  unsigned short* Vtb = Kb  + (size_t)MROWS * HIDDEN;
  unsigned short* Ob  = Vtb + (size_t)MROWS * HIDDEN;

  int n4x = MROWS * HIDDEN / 4;     // 2,097,152
  int n4w = HIDDEN * HIDDEN / 4;    // 1,048,576
  k_cvt<<<(n4x + 255) / 256, 256, 0, stream>>>(x,  xb,  n4x);
  k_cvt<<<(n4w + 255) / 256, 256, 0, stream>>>(Wq, wqb, n4w);
  k_cvt<<<(n4w + 255) / 256, 256, 0, stream>>>(Wk, wkb, n4w);
  k_cvt<<<(n4w + 255) / 256, 256, 0, stream>>>(Wv, wvb, n4w);
  k_cvt<<<(n4w + 255) / 256, 256, 0, stream>>>(Wo, wob, n4w);

  dim3 gg(HIDDEN / 128, MROWS / 128);   // (16, 32)
  k_gemm<0><<<gg, 256, 0, stream>>>(xb, wqb, Qb,  MROWS, HIDDEN, HIDDEN);
  k_gemm<0><<<gg, 256, 0, stream>>>(xb, wkb, Kb,  MROWS, HIDDEN, HIDDEN);
  k_gemm<1><<<gg, 256, 0, stream>>>(xb, wvb, Vtb, MROWS, HIDDEN, HIDDEN);

  k_rope<<<(BATCH * HEADS * SEQ * 8) / 256, 256, 0, stream>>>(Qb, Kb);

  k_attn<<<dim3(SEQ / QB, BATCH * HEADS), 512, 0, stream>>>(Qb, Kb, Vtb, Ob);

  k_gemm<2><<<gg, 256, 0, stream>>>(Ob, wob, out, MROWS, HIDDEN, HIDDEN);
}

// Round 6
// 279.161 us; speedup vs baseline: 2.0657x; 1.0793x over previous
//
#include <hip/hip_runtime.h>
#include <hip/hip_bf16.h>
#include <cstdint>
#include <cstddef>

// Problem constants
constexpr int HIDDEN = 2048;
constexpr int HEADS  = 16;
constexpr int HD     = 128;       // head dim
constexpr int BATCH  = 2;
constexpr int SEQ    = 2048;
constexpr int MROWS  = BATCH * SEQ;   // 4096 rows for all GEMMs

typedef __attribute__((ext_vector_type(8))) short bf16x8;
typedef __attribute__((ext_vector_type(4))) float f32x4;

__device__ __forceinline__ unsigned short f2bf(float f) {
  union { float f; unsigned int u; } c; c.f = f;
  unsigned int r = c.u + 0x7FFFu + ((c.u >> 16) & 1u);
  return (unsigned short)(r >> 16);
}
__device__ __forceinline__ unsigned short f2bft(float f) {   // truncating (1 op)
  union { float f; unsigned int u; } c; c.f = f;
  return (unsigned short)(c.u >> 16);
}
__device__ __forceinline__ float bf2f(unsigned short u) {
  union { unsigned int u; float f; } c; c.u = ((unsigned int)u) << 16;
  return c.f;
}

__device__ __forceinline__ void gload_lds16(const void* g, void* l) {
  __builtin_amdgcn_global_load_lds(
      (const __attribute__((address_space(1))) void*)g,
      (__attribute__((address_space(3))) void*)l, 16, 0, 0);
}

// ---------------- fp32 -> bf16 conversion (vectorized float4) ----------------
__global__ void k_cvt(const float* __restrict__ in, unsigned short* __restrict__ out, int n4) {
  int i = blockIdx.x * 256 + threadIdx.x;
  if (i >= n4) return;
  float4 v = reinterpret_cast<const float4*>(in)[i];
  ushort4 o;
  o.x = f2bf(v.x); o.y = f2bf(v.y); o.z = f2bf(v.z); o.w = f2bf(v.w);
  reinterpret_cast<ushort4*>(out)[i] = o;
}

// all four weights in one launch; outputs are contiguous (wqb,wkb,wvb,wob)
__global__ void k_cvtw(const float* __restrict__ w0, const float* __restrict__ w1,
                       const float* __restrict__ w2, const float* __restrict__ w3,
                       unsigned short* __restrict__ out) {
  constexpr int N4W = HIDDEN * HIDDEN / 4;   // 1048576 = 2^20
  int idx = blockIdx.x * 256 + threadIdx.x;  // 4*N4W threads
  int seg = idx >> 20;
  int off = idx & (N4W - 1);
  const float* src = (seg == 0) ? w0 : (seg == 1) ? w1 : (seg == 2) ? w2 : w3;
  float4 v = reinterpret_cast<const float4*>(src)[off];
  ushort4 o;
  o.x = f2bf(v.x); o.y = f2bf(v.y); o.z = f2bf(v.z); o.w = f2bf(v.w);
  reinterpret_cast<ushort4*>(out)[idx] = o;
}

// ---------------- NT GEMM: C[M,N] = A[M,K] * B[N,K]^T, bf16 in, fp32 acc ----
// MODE 0: fused QK projection. col<2048 -> Q, col>=2048 -> K; bf16 [B,H,S,D].
//         (Cout = Qb; Kb lives at Qb + MROWS*HIDDEN, contiguous in ws.)
// MODE 2: write fp32 row-major [M,N] (final output)
// MODE 3: V^T projection: A=Wv (M=2048), B=x (N=4096); C[o][m] stored to
//         [B,H,D,S] with lanes writing consecutive s -> coalesced.
template<int MODE>
__global__ __launch_bounds__(256, 2) void k_gemm(const unsigned short* __restrict__ A,
                                                 const unsigned short* __restrict__ Bm,
                                                 void* __restrict__ Cout,
                                                 int M, int N, int K) {
  __shared__ unsigned short As[128 * 32];
  __shared__ unsigned short Bs[128 * 32];
  const int t    = threadIdx.x;
  const int lane = t & 63;
  const int w    = t >> 6;
  const int wr   = w >> 1, wc = w & 1;
  const int m0   = blockIdx.y * 128;
  const int n0   = blockIdx.x * 128;
  const int l15  = lane & 15, lg = lane >> 4;

  f32x4 acc[4][4];
#pragma unroll
  for (int mi = 0; mi < 4; ++mi)
#pragma unroll
    for (int ni = 0; ni < 4; ++ni)
#pragma unroll
      for (int r = 0; r < 4; ++r) acc[mi][ni][r] = 0.f;

  const int rowA = t >> 2;          // 0..63
  const int col8 = (t & 3) * 8;
  const unsigned short* gA0 = A  + (size_t)(m0 + rowA) * K + col8;
  const unsigned short* gA1 = gA0 + (size_t)64 * K;
  const unsigned short* gB0 = Bm + (size_t)(n0 + rowA) * K + col8;
  const unsigned short* gB1 = gB0 + (size_t)64 * K;
  unsigned short* lA0 = As + t * 8;            // byte offset t*16 (linear per wave)
  unsigned short* lA1 = As + 64 * 32 + t * 8;
  unsigned short* lB0 = Bs + t * 8;
  unsigned short* lB1 = Bs + 64 * 32 + t * 8;

  for (int k0 = 0; k0 < K; k0 += 32) {
    gload_lds16(gA0 + k0, lA0);
    gload_lds16(gA1 + k0, lA1);
    gload_lds16(gB0 + k0, lB0);
    gload_lds16(gB1 + k0, lB1);
    __syncthreads();   // compiler emits vmcnt(0) drain before s_barrier

    bf16x8 a[4], b[4];
#pragma unroll
    for (int i = 0; i < 4; ++i)
      a[i] = *reinterpret_cast<const bf16x8*>(&As[(wr * 64 + i * 16 + l15) * 32 + lg * 8]);
#pragma unroll
    for (int i = 0; i < 4; ++i)
      b[i] = *reinterpret_cast<const bf16x8*>(&Bs[(wc * 64 + i * 16 + l15) * 32 + lg * 8]);
#pragma unroll
    for (int mi = 0; mi < 4; ++mi)
#pragma unroll
      for (int ni = 0; ni < 4; ++ni)
        acc[mi][ni] = __builtin_amdgcn_mfma_f32_16x16x32_bf16(a[mi], b[ni], acc[mi][ni], 0, 0, 0);
    __syncthreads();   // protect LDS from next iteration's staging
  }

  // Epilogue.  C/D layout: col = lane&15, row = (lane>>4)*4 + r  [m89-verified]
#pragma unroll
  for (int mi = 0; mi < 4; ++mi) {
#pragma unroll
    for (int ni = 0; ni < 4; ++ni) {
#pragma unroll
      for (int r = 0; r < 4; ++r) {
        int row = m0 + wr * 64 + mi * 16 + lg * 4 + r;
        int col = n0 + wc * 64 + ni * 16 + l15;
        float v = acc[mi][ni][r];
        if (MODE == 2) {
          reinterpret_cast<float*>(Cout)[(size_t)row * N + col] = v;
        } else if (MODE == 0) {
          // row = b*SEQ + s;  col = which*2048 + h*128 + d
          int b = row >> 11, s = row & (SEQ - 1);
          int which = col >> 11;
          int hc = col & 2047;
          int h = hc >> 7, d = hc & (HD - 1);
          size_t addr = (size_t)which * ((size_t)MROWS * HIDDEN)
                      + ((size_t)(b * HEADS + h) * SEQ + s) * HD + d;
          reinterpret_cast<unsigned short*>(Cout)[addr] = f2bf(v);
        } else {  // MODE 3: row = output dim o; col = b*SEQ + s
          int h = row >> 7, d = row & (HD - 1);
          int b = col >> 11, s = col & (SEQ - 1);
          size_t addr = ((size_t)(b * HEADS + h) * HD + d) * SEQ + s;
          reinterpret_cast<unsigned short*>(Cout)[addr] = f2bf(v);
        }
      }
    }
  }
}

// ---------------- RoPE on Q and K in [B,H,S,D] bf16 layout ----------------
// thread handles 8 (d, d+64) pairs for one (bh, s).
// Q additionally scaled by 1/sqrt(HD) * log2(e) so attention softmax can use
// native-rate exp2 with no per-element multiplies.
constexpr float QSCALE = 0.08838834764831845f * 1.4426950408889634f;

__global__ void k_rope(unsigned short* __restrict__ Qb, unsigned short* __restrict__ Kb) {
  int idx = blockIdx.x * 256 + threadIdx.x;  // 32 * 2048 * 8 = 524288 threads
  int c  = idx & 7;
  int s  = (idx >> 3) & (SEQ - 1);
  int bh = idx >> 14;
  size_t base = ((size_t)bh * SEQ + s) * HD + c * 8;

  bf16x8 ql = *reinterpret_cast<const bf16x8*>(Qb + base);
  bf16x8 qh = *reinterpret_cast<const bf16x8*>(Qb + base + 64);
  bf16x8 kl = *reinterpret_cast<const bf16x8*>(Kb + base);
  bf16x8 kh = *reinterpret_cast<const bf16x8*>(Kb + base + 64);
  bf16x8 qlo, qho, klo, kho;
#pragma unroll
  for (int j = 0; j < 8; ++j) {
    float d   = (float)(c * 8 + j);
    // inv_freq = 10000^(-d/64) = exp(-d * ln(10000)/64)
    float ang = (float)s * expf(d * -0.14391156511756683f);
    float sn, cs;
    __sincosf(ang, &sn, &cs);
    float a0 = bf2f((unsigned short)ql[j]), a1 = bf2f((unsigned short)qh[j]);
    qlo[j] = (short)f2bf((a0 * cs - a1 * sn) * QSCALE);
    qho[j] = (short)f2bf((a1 * cs + a0 * sn) * QSCALE);
    float b0 = bf2f((unsigned short)kl[j]), b1 = bf2f((unsigned short)kh[j]);
    klo[j] = (short)f2bf(b0 * cs - b1 * sn);
    kho[j] = (short)f2bf(b1 * cs + b0 * sn);
  }
  *reinterpret_cast<bf16x8*>(Qb + base)      = qlo;
  *reinterpret_cast<bf16x8*>(Qb + base + 64) = qho;
  *reinterpret_cast<bf16x8*>(Kb + base)      = klo;
  *reinterpret_cast<bf16x8*>(Kb + base + 64) = kho;
}

// ---------------- causal flash attention (v6) ----------------
// v6 vs v5: scores arrive pre-scaled into log2 domain (QSCALE folded into Q at
// RoPE) -> exp2f softmax, no per-element scale mul; truncating P->bf16;
// s_setprio(1) around MFMA clusters (T5).  Structure otherwise = v5.
constexpr int QB  = 128;   // q rows per block
constexpr int KVB = 64;    // kv rows per iteration
constexpr int NQT = SEQ / QB;   // 16 q-tiles per bh

__global__ __launch_bounds__(512)
__attribute__((amdgpu_waves_per_eu(4, 4)))
void k_attn(const unsigned short* __restrict__ Q,
            const unsigned short* __restrict__ Kk,
            const unsigned short* __restrict__ Vt,
            unsigned short* __restrict__ O) {
  // K dbuf 2x16K + V dbuf 2x16K + P 8x2K = 80 KB -> 2 blocks/CU
  __shared__ char lds[2 * 16384 + 2 * 16384 + 16384];
  char* Ks = lds;
  char* Vs = lds + 2 * 16384;
  char* Ps = lds + 4 * 16384;

  const int t    = threadIdx.x;
  const int lane = t & 63;
  const int w    = t >> 6;
  const int l15  = lane & 15, lg = lane >> 4;
  const int bh   = blockIdx.y;
  const int b    = bh >> 4, h = bh & 15;
  // mirror-flip for the second half of the dispatch order: CU gets (x, 15-x)
  const int qt   = (bh >= HEADS) ? (NQT - 1 - (int)blockIdx.x) : (int)blockIdx.x;
  const int q0b  = qt * QB;
  const int q0w  = q0b + w * 16;
  const int qw_hi = q0w + 15;

  const unsigned short* Qb = Q  + (size_t)bh * SEQ * HD;
  const unsigned short* Kb = Kk + (size_t)bh * SEQ * HD;
  const unsigned short* Vb = Vt + (size_t)bh * HD * SEQ;

  // Q fragments hoisted (A-operand: row = lane&15 -> q, k = (lane>>4)*8+i -> d)
  bf16x8 qf[4];
#pragma unroll
  for (int c = 0; c < 4; ++c)
    qf[c] = *reinterpret_cast<const bf16x8*>(Qb + (size_t)(q0w + l15) * HD + c * 32 + lg * 8);

  float mrow[4], lpart[4];
  f32x4 oacc[8];
#pragma unroll
  for (int r = 0; r < 4; ++r) { mrow[r] = -1e30f; lpart[r] = 0.f; }
#pragma unroll
  for (int dt = 0; dt < 8; ++dt)
#pragma unroll
    for (int r = 0; r < 4; ++r) oacc[dt][r] = 0.f;

  // K staging: LDS linear dest, inverse-swizzled global source (rule #21).
  // K LDS tile = 64 rows x 256B; byte p: row = p>>8, byte (p&255)^((row&7)<<4)
  const int sp     = t * 16;
  const int srow   = sp >> 8;
  const int scolb  = (sp & 255) ^ ((srow & 7) << 4);
  const unsigned short* ksrc2 = Kb + (size_t)srow * HD + (scolb >> 1);
  char* kdst2 = Ks + sp;

  // V staging: V tile = 128 rows x 128B; byte p: row = p>>7, byte (p&127)^((row&7)<<4)
  const int vrow  = t >> 3;                              // 0..63
  const int vcolb = ((t & 7) << 4) ^ ((vrow & 7) << 4);
  const unsigned short* vsrc = Vb + (size_t)vrow * SEQ + (vcolb >> 1);
  char* vdst = Vs + t * 16;

  const int nb = q0b / KVB + 2;                  // covers kv <= q0b+127

  // prologue: stage K,V tile 0 into buffer 0
  gload_lds16(ksrc2, kdst2);
  gload_lds16(ksrc2 + (size_t)32 * HD, kdst2 + 8192);
  gload_lds16(vsrc, vdst);
  gload_lds16(vsrc + (size_t)64 * SEQ, vdst + 8192);
  __syncthreads();

  int cur = 0;
  for (int kb = 0; kb < nb; ++kb) {
    const int kv0 = kb * KVB;
    // prefetch next K,V tile into the other buffer (overlaps with compute below)
    if (kb + 1 < nb) {
      const int nxt = kv0 + KVB;
      char* nk = kdst2 + (cur ^ 1) * 16384;
      char* nv = vdst  + (cur ^ 1) * 16384;
      gload_lds16(ksrc2 + (size_t)nxt * HD, nk);
      gload_lds16(ksrc2 + (size_t)(nxt + 32) * HD, nk + 8192);
      gload_lds16(vsrc + nxt, nv);
      gload_lds16(vsrc + (size_t)64 * SEQ + nxt, nv + 8192);
    }

    if (kv0 <= qw_hi) {          // wave-uniform causal skip
      const char* Kc = Ks + cur * 16384;
      const char* Vc = Vs + cur * 16384;
      // ---- QK^T (scores already scaled & in log2 domain via Q) ----
      f32x4 sc[4];
#pragma unroll
      for (int tt = 0; tt < 4; ++tt)
#pragma unroll
        for (int r = 0; r < 4; ++r) sc[tt][r] = 0.f;
      __builtin_amdgcn_s_setprio(1);
#pragma unroll
      for (int tt = 0; tt < 4; ++tt) {
        const int kr = tt * 16 + l15;
        const int xr = (kr & 7) << 4;
#pragma unroll
        for (int c = 0; c < 4; ++c) {
          bf16x8 kf = *reinterpret_cast<const bf16x8*>(
              Kc + kr * 256 + ((c * 64 + lg * 16) ^ xr));
          sc[tt] = __builtin_amdgcn_mfma_f32_16x16x32_bf16(qf[c], kf, sc[tt], 0, 0, 0);
        }
      }
      __builtin_amdgcn_s_setprio(0);

      // ---- online softmax: __any-gated defer-max (log2 domain, THR 11.5) ----
      const bool full = (kv0 + KVB - 1 <= q0w);   // tile fully unmasked for this wave
#pragma unroll
      for (int r = 0; r < 4; ++r) {
        const int qg = q0w + lg * 4 + r;
        float v0 = sc[0][r], v1 = sc[1][r];
        float v2 = sc[2][r], v3 = sc[3][r];
        if (!full) {
          if (kv0 +      l15 > qg) v0 = -1e30f;
          if (kv0 + 16 + l15 > qg) v1 = -1e30f;
          if (kv0 + 32 + l15 > qg) v2 = -1e30f;
          if (kv0 + 48 + l15 > qg) v3 = -1e30f;
        }
        float pm = fmaxf(fmaxf(v0, v1), fmaxf(v2, v3));   // per-lane only
        if (__any(pm > mrow[r] + 11.5f)) {                // rare: true max reduce
          float pmr = pm;
          pmr = fmaxf(pmr, __shfl_xor(pmr, 1));
          pmr = fmaxf(pmr, __shfl_xor(pmr, 2));
          pmr = fmaxf(pmr, __shfl_xor(pmr, 4));
          pmr = fmaxf(pmr, __shfl_xor(pmr, 8));
          float mn = fmaxf(mrow[r], pmr);
          float al = exp2f(mrow[r] - mn);
          lpart[r] *= al;
#pragma unroll
          for (int dt = 0; dt < 8; ++dt) oacc[dt][r] *= al;
          mrow[r] = mn;
        }
        float p0 = exp2f(v0 - mrow[r]);
        float p1 = exp2f(v1 - mrow[r]);
        float p2 = exp2f(v2 - mrow[r]);
        float p3 = exp2f(v3 - mrow[r]);
        lpart[r] += (p0 + p1) + (p2 + p3);
        // P -> LDS, swizzled (row stride 128B, XOR (row&7)<<4), truncating cvt
        const int prow = lg * 4 + r;
        const int xpr  = (prow & 7) << 4;
        char* pw = Ps + w * 2048 + prow * 128;
        *reinterpret_cast<unsigned short*>(pw + (((0 * 32) + l15 * 2) ^ xpr)) = f2bft(p0);
        *reinterpret_cast<unsigned short*>(pw + (((1 * 32) + l15 * 2) ^ xpr)) = f2bft(p1);
        *reinterpret_cast<unsigned short*>(pw + (((2 * 32) + l15 * 2) ^ xpr)) = f2bft(p2);
        *reinterpret_cast<unsigned short*>(pw + (((3 * 32) + l15 * 2) ^ xpr)) = f2bft(p3);
      }
      asm volatile("s_waitcnt lgkmcnt(0)" ::: "memory");  // wave-local P visibility

      // ---- PV (V from swizzled LDS) ----
      const int xq = (l15 & 7) << 4;
      const char* pr = Ps + w * 2048 + l15 * 128;
      bf16x8 pa0 = *reinterpret_cast<const bf16x8*>(pr + ((0  + lg * 16) ^ xq));
      bf16x8 pa1 = *reinterpret_cast<const bf16x8*>(pr + ((64 + lg * 16) ^ xq));
      const int xv = (l15 & 7) << 4;
      __builtin_amdgcn_s_setprio(1);
#pragma unroll
      for (int dt = 0; dt < 8; ++dt) {
        const char* vrl = Vc + (dt * 16 + l15) * 128;
        bf16x8 vf0 = *reinterpret_cast<const bf16x8*>(vrl + ((lg * 16) ^ xv));
        bf16x8 vf1 = *reinterpret_cast<const bf16x8*>(vrl + ((64 + lg * 16) ^ xv));
        oacc[dt] = __builtin_amdgcn_mfma_f32_16x16x32_bf16(pa0, vf0, oacc[dt], 0, 0, 0);
        oacc[dt] = __builtin_amdgcn_mfma_f32_16x16x32_bf16(pa1, vf1, oacc[dt], 0, 0, 0);
      }
      __builtin_amdgcn_s_setprio(0);
    }
    __syncthreads();   // auto vmcnt(0) drain lands here, AFTER compute
    cur ^= 1;
  }

  // ---- epilogue: reduce deferred sums across the 16 lanes of each row ----
  float inv[4];
#pragma unroll
  for (int r = 0; r < 4; ++r) {
    float ls = lpart[r];
    ls += __shfl_xor(ls, 1);
    ls += __shfl_xor(ls, 2);
    ls += __shfl_xor(ls, 4);
    ls += __shfl_xor(ls, 8);
    inv[r] = 1.0f / ls;
  }
#pragma unroll
  for (int dt = 0; dt < 8; ++dt) {
#pragma unroll
    for (int r = 0; r < 4; ++r) {
      int qg = q0w + lg * 4 + r;
      int dv = dt * 16 + l15;
      O[((size_t)(b * SEQ + qg) * HEADS + h) * HD + dv] = f2bf(oacc[dt][r] * inv[r]);
    }
  }
}

// ---------------- launch ----------------
extern "C" void kernel_launch(void* const* d_in, const int* in_sizes, int n_in,
                              void* d_out, int out_size, void* d_ws, size_t ws_size,
                              hipStream_t stream) {
  (void)in_sizes; (void)n_in; (void)out_size; (void)ws_size;
  const float* x  = (const float*)d_in[0];
  const float* Wq = (const float*)d_in[1];
  const float* Wk = (const float*)d_in[2];
  const float* Wv = (const float*)d_in[3];
  const float* Wo = (const float*)d_in[4];
  float* out = (float*)d_out;

  // workspace layout (bf16 = ushort).  wqb..wob contiguous (k_cvtw relies on
  // it); Qb,Kb contiguous (fused QK epilogue relies on it).
  unsigned short* xb  = (unsigned short*)d_ws;
  unsigned short* wqb = xb  + (size_t)MROWS * HIDDEN;
  unsigned short* wkb = wqb + (size_t)HIDDEN * HIDDEN;
  unsigned short* wvb = wkb + (size_t)HIDDEN * HIDDEN;
  unsigned short* wob = wvb + (size_t)HIDDEN * HIDDEN;
  unsigned short* Qb  = wob + (size_t)HIDDEN * HIDDEN;
  unsigned short* Kb  = Qb  + (size_t)MROWS * HIDDEN;
  unsigned short* Vtb = Kb  + (size_t)MROWS * HIDDEN;
  unsigned short* Ob  = Vtb + (size_t)MROWS * HIDDEN;

  int n4x = MROWS * HIDDEN / 4;     // 2,097,152
  k_cvt<<<(n4x + 255) / 256, 256, 0, stream>>>(x, xb, n4x);
  k_cvtw<<<(4 * HIDDEN * HIDDEN / 4) / 256, 256, 0, stream>>>(Wq, Wk, Wv, Wo, wqb);

  // fused Q+K projection: B = [wqb; wkb] (contiguous), N = 4096
  dim3 gQK(4096 / 128, MROWS / 128);   // (32, 32)
  k_gemm<0><<<gQK, 256, 0, stream>>>(xb, wqb, Qb, MROWS, 4096, HIDDEN);
  // V^T projection (swapped operands -> coalesced [B,H,D,S] stores)
  dim3 gV(MROWS / 128, HIDDEN / 128);  // (32, 16)
  k_gemm<3><<<gV, 256, 0, stream>>>(wvb, xb, Vtb, HIDDEN, MROWS, HIDDEN);

  k_rope<<<(BATCH * HEADS * SEQ * 8) / 256, 256, 0, stream>>>(Qb, Kb);

  k_attn<<<dim3(SEQ / QB, BATCH * HEADS), 512, 0, stream>>>(Qb, Kb, Vtb, Ob);

  dim3 gO(HIDDEN / 128, MROWS / 128);  // (16, 32)
  k_gemm<2><<<gO, 256, 0, stream>>>(Ob, wob, out, MROWS, HIDDEN, HIDDEN);
}

// Round 7
// 258.613 us; speedup vs baseline: 2.2299x; 1.0795x over previous
//
#include <hip/hip_runtime.h>
#include <hip/hip_bf16.h>
#include <cstdint>
#include <cstddef>

// Problem constants
constexpr int HIDDEN = 2048;
constexpr int HEADS  = 16;
constexpr int HD     = 128;       // head dim
constexpr int BATCH  = 2;
constexpr int SEQ    = 2048;
constexpr int MROWS  = BATCH * SEQ;   // 4096 rows for all GEMMs

typedef __attribute__((ext_vector_type(8))) short bf16x8;
typedef __attribute__((ext_vector_type(4))) float f32x4;

__device__ __forceinline__ unsigned short f2bf(float f) {
  union { float f; unsigned int u; } c; c.f = f;
  unsigned int r = c.u + 0x7FFFu + ((c.u >> 16) & 1u);
  return (unsigned short)(r >> 16);
}
__device__ __forceinline__ unsigned short f2bft(float f) {   // truncating (1 op)
  union { float f; unsigned int u; } c; c.f = f;
  return (unsigned short)(c.u >> 16);
}
__device__ __forceinline__ float bf2f(unsigned short u) {
  union { unsigned int u; float f; } c; c.u = ((unsigned int)u) << 16;
  return c.f;
}

__device__ __forceinline__ void gload_lds16(const void* g, void* l) {
  __builtin_amdgcn_global_load_lds(
      (const __attribute__((address_space(1))) void*)g,
      (__attribute__((address_space(3))) void*)l, 16, 0, 0);
}

// ---------------- fp32 -> bf16 conversion: x + all 4 weights, one launch ----
// dest layout (contiguous in ws): xb (2M float4) | wq | wk | wv | wo (1M each)
__global__ void k_cvt_all(const float* __restrict__ x,
                          const float* __restrict__ w0, const float* __restrict__ w1,
                          const float* __restrict__ w2, const float* __restrict__ w3,
                          unsigned short* __restrict__ out) {
  constexpr int N4X = MROWS * HIDDEN / 4;    // 2,097,152
  constexpr int N4W = HIDDEN * HIDDEN / 4;   // 1,048,576 = 2^20
  int idx = blockIdx.x * 256 + threadIdx.x;  // N4X + 4*N4W threads
  const float* src;
  int off;
  if (idx < N4X) { src = x; off = idx; }
  else {
    int j = idx - N4X;
    int seg = j >> 20;
    off = j & (N4W - 1);
    src = (seg == 0) ? w0 : (seg == 1) ? w1 : (seg == 2) ? w2 : w3;
  }
  float4 v = reinterpret_cast<const float4*>(src)[off];
  ushort4 o;
  o.x = f2bf(v.x); o.y = f2bf(v.y); o.z = f2bf(v.z); o.w = f2bf(v.w);
  reinterpret_cast<ushort4*>(out)[idx] = o;
}

// ---------------- 256x256 pipelined NT GEMM (fused QK projection) ----------
// C[M=4096, N=4096] = A[M,K=2048] * B[N,K]^T, bf16, fp32 acc.
// 8 waves (2M x 4N), wave tile 128x64.  BK=64, double-buffered 128 KB LDS,
// XOR-swizzled rows (byte ^= (row&7)<<4).  Raw s_barrier (no vmcnt drain),
// counted vmcnt(8): stage tile kt+2 while computing kt; tile kt+1 in flight.
// Epilogue: col<2048 -> Q, col>=2048 -> K, both bf16 [B,H,S,D].
constexpr int GK  = 2048;
constexpr int GNT = GK / 64;      // 32 K-tiles

__global__ __launch_bounds__(512)
__attribute__((amdgpu_waves_per_eu(2)))
void k_gemm256(const unsigned short* __restrict__ A,
               const unsigned short* __restrict__ Bm,
               unsigned short* __restrict__ Cout) {
  // layout: A [2 buf][2 mhalf][128 rows][128 B]  = 64 KB at lds+0
  //         B [2 buf][2 nhalf][128 rows][128 B]  = 64 KB at lds+65536
  __shared__ char lds[131072];
  char* ldsA = lds;
  char* ldsB = lds + 65536;

  const int t    = threadIdx.x;
  const int lane = t & 63;
  const int w    = t >> 6;
  const int wr   = w >> 2;          // 0..1  M half
  const int wc   = w & 3;           // 0..3  N quarter
  const int l15  = lane & 15, lg = lane >> 4;

  // XCD-chunked swizzle: 256 wgs, 8 XCDs -> 32 consecutive logical wgs per XCD
  const int orig = blockIdx.x;
  const int wg   = (orig & 7) * 32 + (orig >> 3);
  const int m0   = (wg >> 4) * 256;
  const int n0   = (wg & 15) * 256;

  // staging: thread t covers LDS bytes t*16 (+8192/+16384/+24576 per gload).
  // byte p in a half: row = p>>7, slot = (p>>4)&7; src col slot = slot^(row&7).
  const int rowA = t >> 3;                         // 0..63
  const int xsel = ((t & 7) ^ (rowA & 7)) * 8;     // element offset in row
  const unsigned short* aS = A  + (size_t)(m0 + rowA) * GK + xsel;
  const unsigned short* bS = Bm + (size_t)(n0 + rowA) * GK + xsel;
  char* aD = ldsA + t * 16;
  char* bD = ldsB + t * 16;

#define STAGE256(buf, kt) do {                                   \
    const unsigned short* ap = aS + (kt) * 64;                   \
    const unsigned short* bp = bS + (kt) * 64;                   \
    char* ad = aD + (buf) * 32768;                               \
    char* bd = bD + (buf) * 32768;                               \
    gload_lds16(ap,                  ad);                        \
    gload_lds16(ap + 64 * GK,        ad + 8192);                 \
    gload_lds16(ap + 128 * GK,       ad + 16384);                \
    gload_lds16(ap + 192 * GK,       ad + 24576);                \
    gload_lds16(bp,                  bd);                        \
    gload_lds16(bp + 64 * GK,        bd + 8192);                 \
    gload_lds16(bp + 128 * GK,       bd + 16384);                \
    gload_lds16(bp + 192 * GK,       bd + 24576);                \
  } while (0)

  // fragment read bases (byte offsets; row&7 == l15&7 since 16 ≡ 0 mod 8)
  const int xr  = (l15 & 7) << 4;
  const int vo0 = (lg * 16) ^ xr;          // ks=0
  const int vo1 = (64 + lg * 16) ^ xr;     // ks=1
  const char* aR = ldsA + wr * 16384 + l15 * 128;
  const char* bR = ldsB + (wc >> 1) * 16384 + (wc & 1) * 8192 + l15 * 128;

  f32x4 acc[8][4];
#pragma unroll
  for (int mi = 0; mi < 8; ++mi)
#pragma unroll
    for (int ni = 0; ni < 4; ++ni)
#pragma unroll
      for (int r = 0; r < 4; ++r) acc[mi][ni][r] = 0.f;

  // prologue: tiles 0 and 1
  STAGE256(0, 0);
  STAGE256(1, 1);
  asm volatile("s_waitcnt vmcnt(8)" ::: "memory");   // tile 0 landed
  __builtin_amdgcn_s_barrier();
  asm volatile("" ::: "memory");

#pragma unroll 1
  for (int kt = 0; kt < GNT; ++kt) {
    const int buf = kt & 1;
    const char* a = aR + buf * 32768;
    const char* b = bR + buf * 32768;

    // ---- ks = 0: reads + MFMA ----
    bf16x8 af0[8], bf0[4];
#pragma unroll
    for (int mi = 0; mi < 8; ++mi)
      af0[mi] = *reinterpret_cast<const bf16x8*>(a + mi * 2048 + vo0);
#pragma unroll
    for (int ni = 0; ni < 4; ++ni)
      bf0[ni] = *reinterpret_cast<const bf16x8*>(b + ni * 2048 + vo0);
    __builtin_amdgcn_s_setprio(1);
#pragma unroll
    for (int mi = 0; mi < 8; ++mi)
#pragma unroll
      for (int ni = 0; ni < 4; ++ni)
        acc[mi][ni] = __builtin_amdgcn_mfma_f32_16x16x32_bf16(af0[mi], bf0[ni], acc[mi][ni], 0, 0, 0);
    __builtin_amdgcn_s_setprio(0);

    // ---- ks = 1: reads ----
    bf16x8 af1[8], bf1[4];
#pragma unroll
    for (int mi = 0; mi < 8; ++mi)
      af1[mi] = *reinterpret_cast<const bf16x8*>(a + mi * 2048 + vo1);
#pragma unroll
    for (int ni = 0; ni < 4; ++ni)
      bf1[ni] = *reinterpret_cast<const bf16x8*>(b + ni * 2048 + vo1);

    // all reads of this buffer done -> safe to overwrite after the barrier
    asm volatile("s_waitcnt lgkmcnt(0)" ::: "memory");
    __builtin_amdgcn_s_barrier();
    asm volatile("" ::: "memory");

    if (kt < GNT - 2) STAGE256(buf, kt + 2);

    __builtin_amdgcn_s_setprio(1);
#pragma unroll
    for (int mi = 0; mi < 8; ++mi)
#pragma unroll
      for (int ni = 0; ni < 4; ++ni)
        acc[mi][ni] = __builtin_amdgcn_mfma_f32_16x16x32_bf16(af1[mi], bf1[ni], acc[mi][ni], 0, 0, 0);
    __builtin_amdgcn_s_setprio(0);

    // wait for tile kt+1 (oldest 8 loads); tile kt+2's 8 stay in flight
    if (kt < GNT - 2) asm volatile("s_waitcnt vmcnt(8)" ::: "memory");
    else              asm volatile("s_waitcnt vmcnt(0)" ::: "memory");
    __builtin_amdgcn_s_barrier();
    asm volatile("" ::: "memory");
  }
#undef STAGE256

  // epilogue: fused QK store.  col<2048 -> Q, else K; both [B,H,S,D] bf16.
#pragma unroll
  for (int mi = 0; mi < 8; ++mi) {
#pragma unroll
    for (int ni = 0; ni < 4; ++ni) {
#pragma unroll
      for (int r = 0; r < 4; ++r) {
        int row = m0 + wr * 128 + mi * 16 + lg * 4 + r;   // b*SEQ + s
        int col = n0 + wc * 64 + ni * 16 + l15;           // which*2048 + h*128 + d
        int bb = row >> 11, s = row & (SEQ - 1);
        int which = col >> 11;
        int hc = col & 2047;
        int h = hc >> 7, d = hc & (HD - 1);
        size_t addr = (size_t)which * ((size_t)MROWS * HIDDEN)
                    + ((size_t)(bb * HEADS + h) * SEQ + s) * HD + d;
        Cout[addr] = f2bf(acc[mi][ni][r]);
      }
    }
  }
}

// ---------------- 128x128 NT GEMM (m97 structure) for V^T and O ------------
// MODE 2: write fp32 row-major [M,N] (final output)
// MODE 3: V^T projection: A=Wv (M=2048), B=x (N=4096); C[o][m] stored to
//         [B,H,D,S] with lanes writing consecutive s -> coalesced.
template<int MODE>
__global__ __launch_bounds__(256, 2) void k_gemm(const unsigned short* __restrict__ A,
                                                 const unsigned short* __restrict__ Bm,
                                                 void* __restrict__ Cout,
                                                 int M, int N, int K) {
  __shared__ unsigned short As[128 * 32];
  __shared__ unsigned short Bs[128 * 32];
  const int t    = threadIdx.x;
  const int lane = t & 63;
  const int w    = t >> 6;
  const int wr   = w >> 1, wc = w & 1;
  const int m0   = blockIdx.y * 128;
  const int n0   = blockIdx.x * 128;
  const int l15  = lane & 15, lg = lane >> 4;

  f32x4 acc[4][4];
#pragma unroll
  for (int mi = 0; mi < 4; ++mi)
#pragma unroll
    for (int ni = 0; ni < 4; ++ni)
#pragma unroll
      for (int r = 0; r < 4; ++r) acc[mi][ni][r] = 0.f;

  const int rowA = t >> 2;          // 0..63
  const int col8 = (t & 3) * 8;
  const unsigned short* gA0 = A  + (size_t)(m0 + rowA) * K + col8;
  const unsigned short* gA1 = gA0 + (size_t)64 * K;
  const unsigned short* gB0 = Bm + (size_t)(n0 + rowA) * K + col8;
  const unsigned short* gB1 = gB0 + (size_t)64 * K;
  unsigned short* lA0 = As + t * 8;
  unsigned short* lA1 = As + 64 * 32 + t * 8;
  unsigned short* lB0 = Bs + t * 8;
  unsigned short* lB1 = Bs + 64 * 32 + t * 8;

  for (int k0 = 0; k0 < K; k0 += 32) {
    gload_lds16(gA0 + k0, lA0);
    gload_lds16(gA1 + k0, lA1);
    gload_lds16(gB0 + k0, lB0);
    gload_lds16(gB1 + k0, lB1);
    __syncthreads();

    bf16x8 a[4], b[4];
#pragma unroll
    for (int i = 0; i < 4; ++i)
      a[i] = *reinterpret_cast<const bf16x8*>(&As[(wr * 64 + i * 16 + l15) * 32 + lg * 8]);
#pragma unroll
    for (int i = 0; i < 4; ++i)
      b[i] = *reinterpret_cast<const bf16x8*>(&Bs[(wc * 64 + i * 16 + l15) * 32 + lg * 8]);
#pragma unroll
    for (int mi = 0; mi < 4; ++mi)
#pragma unroll
      for (int ni = 0; ni < 4; ++ni)
        acc[mi][ni] = __builtin_amdgcn_mfma_f32_16x16x32_bf16(a[mi], b[ni], acc[mi][ni], 0, 0, 0);
    __syncthreads();
  }

#pragma unroll
  for (int mi = 0; mi < 4; ++mi) {
#pragma unroll
    for (int ni = 0; ni < 4; ++ni) {
#pragma unroll
      for (int r = 0; r < 4; ++r) {
        int row = m0 + wr * 64 + mi * 16 + lg * 4 + r;
        int col = n0 + wc * 64 + ni * 16 + l15;
        float v = acc[mi][ni][r];
        if (MODE == 2) {
          reinterpret_cast<float*>(Cout)[(size_t)row * N + col] = v;
        } else {  // MODE 3: row = output dim o; col = b*SEQ + s
          int h = row >> 7, d = row & (HD - 1);
          int b = col >> 11, s = col & (SEQ - 1);
          size_t addr = ((size_t)(b * HEADS + h) * HD + d) * SEQ + s;
          reinterpret_cast<unsigned short*>(Cout)[addr] = f2bf(v);
        }
      }
    }
  }
}

// ---------------- RoPE on Q and K in [B,H,S,D] bf16 layout ----------------
constexpr float QSCALE = 0.08838834764831845f * 1.4426950408889634f;

__global__ void k_rope(unsigned short* __restrict__ Qb, unsigned short* __restrict__ Kb) {
  int idx = blockIdx.x * 256 + threadIdx.x;
  int c  = idx & 7;
  int s  = (idx >> 3) & (SEQ - 1);
  int bh = idx >> 14;
  size_t base = ((size_t)bh * SEQ + s) * HD + c * 8;

  bf16x8 ql = *reinterpret_cast<const bf16x8*>(Qb + base);
  bf16x8 qh = *reinterpret_cast<const bf16x8*>(Qb + base + 64);
  bf16x8 kl = *reinterpret_cast<const bf16x8*>(Kb + base);
  bf16x8 kh = *reinterpret_cast<const bf16x8*>(Kb + base + 64);
  bf16x8 qlo, qho, klo, kho;
#pragma unroll
  for (int j = 0; j < 8; ++j) {
    float d   = (float)(c * 8 + j);
    float ang = (float)s * expf(d * -0.14391156511756683f);
    float sn, cs;
    __sincosf(ang, &sn, &cs);
    float a0 = bf2f((unsigned short)ql[j]), a1 = bf2f((unsigned short)qh[j]);
    qlo[j] = (short)f2bf((a0 * cs - a1 * sn) * QSCALE);
    qho[j] = (short)f2bf((a1 * cs + a0 * sn) * QSCALE);
    float b0 = bf2f((unsigned short)kl[j]), b1 = bf2f((unsigned short)kh[j]);
    klo[j] = (short)f2bf(b0 * cs - b1 * sn);
    kho[j] = (short)f2bf(b1 * cs + b0 * sn);
  }
  *reinterpret_cast<bf16x8*>(Qb + base)      = qlo;
  *reinterpret_cast<bf16x8*>(Qb + base + 64) = qho;
  *reinterpret_cast<bf16x8*>(Kb + base)      = klo;
  *reinterpret_cast<bf16x8*>(Kb + base + 64) = kho;
}

// ---------------- causal flash attention (v6) ----------------
constexpr int QB  = 128;
constexpr int KVB = 64;
constexpr int NQT = SEQ / QB;

__global__ __launch_bounds__(512)
__attribute__((amdgpu_waves_per_eu(4, 4)))
void k_attn(const unsigned short* __restrict__ Q,
            const unsigned short* __restrict__ Kk,
            const unsigned short* __restrict__ Vt,
            unsigned short* __restrict__ O) {
  __shared__ char lds[2 * 16384 + 2 * 16384 + 16384];
  char* Ks = lds;
  char* Vs = lds + 2 * 16384;
  char* Ps = lds + 4 * 16384;

  const int t    = threadIdx.x;
  const int lane = t & 63;
  const int w    = t >> 6;
  const int l15  = lane & 15, lg = lane >> 4;
  const int bh   = blockIdx.y;
  const int b    = bh >> 4, h = bh & 15;
  const int qt   = (bh >= HEADS) ? (NQT - 1 - (int)blockIdx.x) : (int)blockIdx.x;
  const int q0b  = qt * QB;
  const int q0w  = q0b + w * 16;
  const int qw_hi = q0w + 15;

  const unsigned short* Qb = Q  + (size_t)bh * SEQ * HD;
  const unsigned short* Kb = Kk + (size_t)bh * SEQ * HD;
  const unsigned short* Vb = Vt + (size_t)bh * HD * SEQ;

  bf16x8 qf[4];
#pragma unroll
  for (int c = 0; c < 4; ++c)
    qf[c] = *reinterpret_cast<const bf16x8*>(Qb + (size_t)(q0w + l15) * HD + c * 32 + lg * 8);

  float mrow[4], lpart[4];
  f32x4 oacc[8];
#pragma unroll
  for (int r = 0; r < 4; ++r) { mrow[r] = -1e30f; lpart[r] = 0.f; }
#pragma unroll
  for (int dt = 0; dt < 8; ++dt)
#pragma unroll
    for (int r = 0; r < 4; ++r) oacc[dt][r] = 0.f;

  const int sp     = t * 16;
  const int srow   = sp >> 8;
  const int scolb  = (sp & 255) ^ ((srow & 7) << 4);
  const unsigned short* ksrc2 = Kb + (size_t)srow * HD + (scolb >> 1);
  char* kdst2 = Ks + sp;

  const int vrow  = t >> 3;
  const int vcolb = ((t & 7) << 4) ^ ((vrow & 7) << 4);
  const unsigned short* vsrc = Vb + (size_t)vrow * SEQ + (vcolb >> 1);
  char* vdst = Vs + t * 16;

  const int nb = q0b / KVB + 2;

  gload_lds16(ksrc2, kdst2);
  gload_lds16(ksrc2 + (size_t)32 * HD, kdst2 + 8192);
  gload_lds16(vsrc, vdst);
  gload_lds16(vsrc + (size_t)64 * SEQ, vdst + 8192);
  __syncthreads();

  int cur = 0;
  for (int kb = 0; kb < nb; ++kb) {
    const int kv0 = kb * KVB;
    if (kb + 1 < nb) {
      const int nxt = kv0 + KVB;
      char* nk = kdst2 + (cur ^ 1) * 16384;
      char* nv = vdst  + (cur ^ 1) * 16384;
      gload_lds16(ksrc2 + (size_t)nxt * HD, nk);
      gload_lds16(ksrc2 + (size_t)(nxt + 32) * HD, nk + 8192);
      gload_lds16(vsrc + nxt, nv);
      gload_lds16(vsrc + (size_t)64 * SEQ + nxt, nv + 8192);
    }

    if (kv0 <= qw_hi) {
      const char* Kc = Ks + cur * 16384;
      const char* Vc = Vs + cur * 16384;
      f32x4 sc[4];
#pragma unroll
      for (int tt = 0; tt < 4; ++tt)
#pragma unroll
        for (int r = 0; r < 4; ++r) sc[tt][r] = 0.f;
      __builtin_amdgcn_s_setprio(1);
#pragma unroll
      for (int tt = 0; tt < 4; ++tt) {
        const int kr = tt * 16 + l15;
        const int xr = (kr & 7) << 4;
#pragma unroll
        for (int c = 0; c < 4; ++c) {
          bf16x8 kf = *reinterpret_cast<const bf16x8*>(
              Kc + kr * 256 + ((c * 64 + lg * 16) ^ xr));
          sc[tt] = __builtin_amdgcn_mfma_f32_16x16x32_bf16(qf[c], kf, sc[tt], 0, 0, 0);
        }
      }
      __builtin_amdgcn_s_setprio(0);

      const bool full = (kv0 + KVB - 1 <= q0w);
#pragma unroll
      for (int r = 0; r < 4; ++r) {
        const int qg = q0w + lg * 4 + r;
        float v0 = sc[0][r], v1 = sc[1][r];
        float v2 = sc[2][r], v3 = sc[3][r];
        if (!full) {
          if (kv0 +      l15 > qg) v0 = -1e30f;
          if (kv0 + 16 + l15 > qg) v1 = -1e30f;
          if (kv0 + 32 + l15 > qg) v2 = -1e30f;
          if (kv0 + 48 + l15 > qg) v3 = -1e30f;
        }
        float pm = fmaxf(fmaxf(v0, v1), fmaxf(v2, v3));
        if (__any(pm > mrow[r] + 11.5f)) {
          float pmr = pm;
          pmr = fmaxf(pmr, __shfl_xor(pmr, 1));
          pmr = fmaxf(pmr, __shfl_xor(pmr, 2));
          pmr = fmaxf(pmr, __shfl_xor(pmr, 4));
          pmr = fmaxf(pmr, __shfl_xor(pmr, 8));
          float mn = fmaxf(mrow[r], pmr);
          float al = exp2f(mrow[r] - mn);
          lpart[r] *= al;
#pragma unroll
          for (int dt = 0; dt < 8; ++dt) oacc[dt][r] *= al;
          mrow[r] = mn;
        }
        float p0 = exp2f(v0 - mrow[r]);
        float p1 = exp2f(v1 - mrow[r]);
        float p2 = exp2f(v2 - mrow[r]);
        float p3 = exp2f(v3 - mrow[r]);
        lpart[r] += (p0 + p1) + (p2 + p3);
        const int prow = lg * 4 + r;
        const int xpr  = (prow & 7) << 4;
        char* pw = Ps + w * 2048 + prow * 128;
        *reinterpret_cast<unsigned short*>(pw + (((0 * 32) + l15 * 2) ^ xpr)) = f2bft(p0);
        *reinterpret_cast<unsigned short*>(pw + (((1 * 32) + l15 * 2) ^ xpr)) = f2bft(p1);
        *reinterpret_cast<unsigned short*>(pw + (((2 * 32) + l15 * 2) ^ xpr)) = f2bft(p2);
        *reinterpret_cast<unsigned short*>(pw + (((3 * 32) + l15 * 2) ^ xpr)) = f2bft(p3);
      }
      asm volatile("s_waitcnt lgkmcnt(0)" ::: "memory");

      const int xq = (l15 & 7) << 4;
      const char* pr = Ps + w * 2048 + l15 * 128;
      bf16x8 pa0 = *reinterpret_cast<const bf16x8*>(pr + ((0  + lg * 16) ^ xq));
      bf16x8 pa1 = *reinterpret_cast<const bf16x8*>(pr + ((64 + lg * 16) ^ xq));
      const int xv = (l15 & 7) << 4;
      __builtin_amdgcn_s_setprio(1);
#pragma unroll
      for (int dt = 0; dt < 8; ++dt) {
        const char* vrl = Vc + (dt * 16 + l15) * 128;
        bf16x8 vf0 = *reinterpret_cast<const bf16x8*>(vrl + ((lg * 16) ^ xv));
        bf16x8 vf1 = *reinterpret_cast<const bf16x8*>(vrl + ((64 + lg * 16) ^ xv));
        oacc[dt] = __builtin_amdgcn_mfma_f32_16x16x32_bf16(pa0, vf0, oacc[dt], 0, 0, 0);
        oacc[dt] = __builtin_amdgcn_mfma_f32_16x16x32_bf16(pa1, vf1, oacc[dt], 0, 0, 0);
      }
      __builtin_amdgcn_s_setprio(0);
    }
    __syncthreads();
    cur ^= 1;
  }

  float inv[4];
#pragma unroll
  for (int r = 0; r < 4; ++r) {
    float ls = lpart[r];
    ls += __shfl_xor(ls, 1);
    ls += __shfl_xor(ls, 2);
    ls += __shfl_xor(ls, 4);
    ls += __shfl_xor(ls, 8);
    inv[r] = 1.0f / ls;
  }
#pragma unroll
  for (int dt = 0; dt < 8; ++dt) {
#pragma unroll
    for (int r = 0; r < 4; ++r) {
      int qg = q0w + lg * 4 + r;
      int dv = dt * 16 + l15;
      O[((size_t)(b * SEQ + qg) * HEADS + h) * HD + dv] = f2bf(oacc[dt][r] * inv[r]);
    }
  }
}

// ---------------- launch ----------------
extern "C" void kernel_launch(void* const* d_in, const int* in_sizes, int n_in,
                              void* d_out, int out_size, void* d_ws, size_t ws_size,
                              hipStream_t stream) {
  (void)in_sizes; (void)n_in; (void)out_size; (void)ws_size;
  const float* x  = (const float*)d_in[0];
  const float* Wq = (const float*)d_in[1];
  const float* Wk = (const float*)d_in[2];
  const float* Wv = (const float*)d_in[3];
  const float* Wo = (const float*)d_in[4];
  float* out = (float*)d_out;

  unsigned short* xb  = (unsigned short*)d_ws;
  unsigned short* wqb = xb  + (size_t)MROWS * HIDDEN;
  unsigned short* wkb = wqb + (size_t)HIDDEN * HIDDEN;
  unsigned short* wvb = wkb + (size_t)HIDDEN * HIDDEN;
  unsigned short* wob = wvb + (size_t)HIDDEN * HIDDEN;
  unsigned short* Qb  = wob + (size_t)HIDDEN * HIDDEN;
  unsigned short* Kb  = Qb  + (size_t)MROWS * HIDDEN;
  unsigned short* Vtb = Kb  + (size_t)MROWS * HIDDEN;
  unsigned short* Ob  = Vtb + (size_t)MROWS * HIDDEN;

  // single conversion launch: x + 4 weights (dest contiguous from xb)
  constexpr int CVT_THREADS = (MROWS * HIDDEN + 4 * HIDDEN * HIDDEN) / 4;
  k_cvt_all<<<CVT_THREADS / 256, 256, 0, stream>>>(x, Wq, Wk, Wv, Wo, xb);

  // fused Q+K projection: 256x256 pipelined kernel, 256 blocks
  k_gemm256<<<256, 512, 0, stream>>>(xb, wqb, Qb);
  // V^T projection (swapped operands -> coalesced [B,H,D,S] stores)
  dim3 gV(MROWS / 128, HIDDEN / 128);  // (32, 16)
  k_gemm<3><<<gV, 256, 0, stream>>>(wvb, xb, Vtb, HIDDEN, MROWS, HIDDEN);

  k_rope<<<(BATCH * HEADS * SEQ * 8) / 256, 256, 0, stream>>>(Qb, Kb);

  k_attn<<<dim3(SEQ / QB, BATCH * HEADS), 512, 0, stream>>>(Qb, Kb, Vtb, Ob);

  dim3 gO(HIDDEN / 128, MROWS / 128);  // (16, 32)
  k_gemm<2><<<gO, 256, 0, stream>>>(Ob, wob, out, MROWS, HIDDEN, HIDDEN);
}

// Round 8
// 240.772 us; speedup vs baseline: 2.3951x; 1.0741x over previous
//
#include <hip/hip_runtime.h>
#include <hip/hip_bf16.h>
#include <cstdint>
#include <cstddef>

// Problem constants
constexpr int HIDDEN = 2048;
constexpr int HEADS  = 16;
constexpr int HD     = 128;       // head dim
constexpr int BATCH  = 2;
constexpr int SEQ    = 2048;
constexpr int MROWS  = BATCH * SEQ;   // 4096 rows for all GEMMs

typedef __attribute__((ext_vector_type(8))) short bf16x8;
typedef __attribute__((ext_vector_type(4))) float f32x4;

__device__ __forceinline__ unsigned short f2bf(float f) {
  union { float f; unsigned int u; } c; c.f = f;
  unsigned int r = c.u + 0x7FFFu + ((c.u >> 16) & 1u);
  return (unsigned short)(r >> 16);
}
__device__ __forceinline__ unsigned short f2bft(float f) {   // truncating (1 op)
  union { float f; unsigned int u; } c; c.f = f;
  return (unsigned short)(c.u >> 16);
}
__device__ __forceinline__ float bf2f(unsigned short u) {
  union { unsigned int u; float f; } c; c.u = ((unsigned int)u) << 16;
  return c.f;
}

__device__ __forceinline__ void gload_lds16(const void* g, void* l) {
  __builtin_amdgcn_global_load_lds(
      (const __attribute__((address_space(1))) void*)g,
      (__attribute__((address_space(3))) void*)l, 16, 0, 0);
}

// ---------------- fp32 -> bf16 conversion: x + all 4 weights, one launch ----
__global__ void k_cvt_all(const float* __restrict__ x,
                          const float* __restrict__ w0, const float* __restrict__ w1,
                          const float* __restrict__ w2, const float* __restrict__ w3,
                          unsigned short* __restrict__ out) {
  constexpr int N4X = MROWS * HIDDEN / 4;    // 2,097,152
  constexpr int N4W = HIDDEN * HIDDEN / 4;   // 1,048,576 = 2^20
  int idx = blockIdx.x * 256 + threadIdx.x;  // N4X + 4*N4W threads
  const float* src;
  int off;
  if (idx < N4X) { src = x; off = idx; }
  else {
    int j = idx - N4X;
    int seg = j >> 20;
    off = j & (N4W - 1);
    src = (seg == 0) ? w0 : (seg == 1) ? w1 : (seg == 2) ? w2 : w3;
  }
  float4 v = reinterpret_cast<const float4*>(src)[off];
  ushort4 o;
  o.x = f2bf(v.x); o.y = f2bf(v.y); o.z = f2bf(v.z); o.w = f2bf(v.w);
  reinterpret_cast<ushort4*>(out)[idx] = o;
}

// ---------------- pipelined NT GEMM, BM x BN tile, 8 waves (2M x 4N) --------
// C[M,N] = A[M,K=2048] * B[N,K]^T, bf16 in, fp32 acc.  Double-buffered LDS,
// XOR-swizzled rows (byte ^= (row&7)<<4) via pre-swizzled global source.
// Raw s_barrier + counted vmcnt(G): stage tile kt+2 while computing kt.
// Grid must be 256 blocks (16 m-tiles x 16 n-tiles); XCD-chunked swizzle.
// MODE 0: fused QK projection -> bf16 [B,H,S,D] (Q at col<2048, K else)
// MODE 2: fp32 row-major [M, 2048] (final output)
// MODE 3: V^T projection (A=Wv, B=x) -> bf16 [B,H,D,S]
constexpr int GK  = 2048;
constexpr int GNT = GK / 64;      // 32 K-tiles

template<int MODE, int BM, int BN>
__global__ __launch_bounds__(512)
__attribute__((amdgpu_waves_per_eu(2)))
void k_gemm256(const unsigned short* __restrict__ A,
               const unsigned short* __restrict__ Bm,
               void* __restrict__ Cout) {
  constexpr int ABYTES = BM * 64 * 2;       // bytes per A buffer
  constexpr int BBYTES = BN * 64 * 2;
  constexpr int AG = BM / 64;               // gloads per A tile
  constexpr int BG = BN / 64;
  constexpr int G  = AG + BG;               // gloads per tile (vmcnt unit)
  constexpr int MI = BM / 32;               // M fragments per wave (BM/2/16)
  constexpr int NI = BN / 64;               // N fragments per wave (BN/4/16)

  __shared__ char lds[2 * (ABYTES + BBYTES)];
  char* ldsA = lds;                         // [2 buf][ABYTES]
  char* ldsB = lds + 2 * ABYTES;            // [2 buf][BBYTES]

  const int t    = threadIdx.x;
  const int lane = t & 63;
  const int w    = t >> 6;
  const int wr   = w >> 2;          // 0..1  M half
  const int wc   = w & 3;           // 0..3  N quarter
  const int l15  = lane & 15, lg = lane >> 4;

  // XCD-chunked swizzle: 256 wgs, 8 XCDs -> 32 consecutive logical wgs per XCD
  const int orig = blockIdx.x;
  const int wg   = (orig & 7) * 32 + (orig >> 3);
  const int m0   = (wg >> 4) * BM;
  const int n0   = (wg & 15) * BN;

  // staging: each gload covers 8192 B = 64 rows x 128 B.
  // LDS byte p (within a 64-row chunk): row = p>>7, slot = (p>>4)&7;
  // source column slot = slot ^ (row&7)  (inverse swizzle on global source).
  const int rowA = t >> 3;                         // 0..63
  const int xsel = ((t & 7) ^ (rowA & 7)) * 8;     // element offset in row
  const unsigned short* aS = A  + (size_t)(m0 + rowA) * GK + xsel;
  const unsigned short* bS = Bm + (size_t)(n0 + rowA) * GK + xsel;
  char* aD = ldsA + t * 16;
  char* bD = ldsB + t * 16;

#define STAGEG(buf, kt) do {                                       \
    const unsigned short* ap = aS + (kt) * 64;                     \
    const unsigned short* bp = bS + (kt) * 64;                     \
    char* ad = aD + (buf) * ABYTES;                                \
    char* bd = bD + (buf) * BBYTES;                                \
    _Pragma("unroll")                                              \
    for (int g = 0; g < AG; ++g)                                   \
      gload_lds16(ap + (size_t)g * 64 * GK, ad + g * 8192);        \
    _Pragma("unroll")                                              \
    for (int g = 0; g < BG; ++g)                                   \
      gload_lds16(bp + (size_t)g * 64 * GK, bd + g * 8192);        \
  } while (0)

  // fragment read bases (byte offsets; row&7 == l15&7 since 16 ≡ 0 mod 8)
  const int xr  = (l15 & 7) << 4;
  const int vo0 = (lg * 16) ^ xr;          // ks=0
  const int vo1 = (64 + lg * 16) ^ xr;     // ks=1
  const char* aR = ldsA + wr * (BM / 2) * 128 + l15 * 128;
  const char* bR = ldsB + wc * (BN / 4) * 128 + l15 * 128;

  f32x4 acc[MI][NI];
#pragma unroll
  for (int mi = 0; mi < MI; ++mi)
#pragma unroll
    for (int ni = 0; ni < NI; ++ni)
#pragma unroll
      for (int r = 0; r < 4; ++r) acc[mi][ni][r] = 0.f;

  // prologue: tiles 0 and 1
  STAGEG(0, 0);
  STAGEG(1, 1);
  asm volatile("s_waitcnt vmcnt(%0)" :: "i"(G) : "memory");   // tile 0 landed
  __builtin_amdgcn_s_barrier();
  asm volatile("" ::: "memory");

#pragma unroll 1
  for (int kt = 0; kt < GNT; ++kt) {
    const int buf = kt & 1;
    const char* a = aR + buf * ABYTES;
    const char* b = bR + buf * BBYTES;

    // ---- ks = 0: reads + MFMA ----
    bf16x8 af0[MI], bf0[NI];
#pragma unroll
    for (int mi = 0; mi < MI; ++mi)
      af0[mi] = *reinterpret_cast<const bf16x8*>(a + mi * 2048 + vo0);
#pragma unroll
    for (int ni = 0; ni < NI; ++ni)
      bf0[ni] = *reinterpret_cast<const bf16x8*>(b + ni * 2048 + vo0);
    __builtin_amdgcn_s_setprio(1);
#pragma unroll
    for (int mi = 0; mi < MI; ++mi)
#pragma unroll
      for (int ni = 0; ni < NI; ++ni)
        acc[mi][ni] = __builtin_amdgcn_mfma_f32_16x16x32_bf16(af0[mi], bf0[ni], acc[mi][ni], 0, 0, 0);
    __builtin_amdgcn_s_setprio(0);

    // ---- ks = 1: reads ----
    bf16x8 af1[MI], bf1[NI];
#pragma unroll
    for (int mi = 0; mi < MI; ++mi)
      af1[mi] = *reinterpret_cast<const bf16x8*>(a + mi * 2048 + vo1);
#pragma unroll
    for (int ni = 0; ni < NI; ++ni)
      bf1[ni] = *reinterpret_cast<const bf16x8*>(b + ni * 2048 + vo1);

    // all reads of this buffer done -> safe to overwrite after the barrier
    asm volatile("s_waitcnt lgkmcnt(0)" ::: "memory");
    __builtin_amdgcn_s_barrier();
    asm volatile("" ::: "memory");

    if (kt < GNT - 2) STAGEG(buf, kt + 2);

    __builtin_amdgcn_s_setprio(1);
#pragma unroll
    for (int mi = 0; mi < MI; ++mi)
#pragma unroll
      for (int ni = 0; ni < NI; ++ni)
        acc[mi][ni] = __builtin_amdgcn_mfma_f32_16x16x32_bf16(af1[mi], bf1[ni], acc[mi][ni], 0, 0, 0);
    __builtin_amdgcn_s_setprio(0);

    // wait for tile kt+1 (oldest G loads); tile kt+2's G stay in flight
    if (kt < GNT - 2) asm volatile("s_waitcnt vmcnt(%0)" :: "i"(G) : "memory");
    else              asm volatile("s_waitcnt vmcnt(0)" ::: "memory");
    __builtin_amdgcn_s_barrier();
    asm volatile("" ::: "memory");
  }
#undef STAGEG

  // epilogue
#pragma unroll
  for (int mi = 0; mi < MI; ++mi) {
#pragma unroll
    for (int ni = 0; ni < NI; ++ni) {
#pragma unroll
      for (int r = 0; r < 4; ++r) {
        int row = m0 + wr * (BM / 2) + mi * 16 + lg * 4 + r;
        int col = n0 + wc * (BN / 4) + ni * 16 + l15;
        float v = acc[mi][ni][r];
        if (MODE == 2) {
          reinterpret_cast<float*>(Cout)[(size_t)row * 2048 + col] = v;
        } else if (MODE == 0) {
          // row = b*SEQ + s;  col = which*2048 + h*128 + d
          int bb = row >> 11, s = row & (SEQ - 1);
          int which = col >> 11;
          int hc = col & 2047;
          int h = hc >> 7, d = hc & (HD - 1);
          size_t addr = (size_t)which * ((size_t)MROWS * HIDDEN)
                      + ((size_t)(bb * HEADS + h) * SEQ + s) * HD + d;
          reinterpret_cast<unsigned short*>(Cout)[addr] = f2bf(v);
        } else {  // MODE 3: row = output dim o; col = b*SEQ + s
          int h = row >> 7, d = row & (HD - 1);
          int bb = col >> 11, s = col & (SEQ - 1);
          size_t addr = ((size_t)(bb * HEADS + h) * HD + d) * SEQ + s;
          reinterpret_cast<unsigned short*>(Cout)[addr] = f2bf(v);
        }
      }
    }
  }
}

// ---------------- RoPE on Q and K in [B,H,S,D] bf16 layout ----------------
constexpr float QSCALE = 0.08838834764831845f * 1.4426950408889634f;

__global__ void k_rope(unsigned short* __restrict__ Qb, unsigned short* __restrict__ Kb) {
  int idx = blockIdx.x * 256 + threadIdx.x;
  int c  = idx & 7;
  int s  = (idx >> 3) & (SEQ - 1);
  int bh = idx >> 14;
  size_t base = ((size_t)bh * SEQ + s) * HD + c * 8;

  bf16x8 ql = *reinterpret_cast<const bf16x8*>(Qb + base);
  bf16x8 qh = *reinterpret_cast<const bf16x8*>(Qb + base + 64);
  bf16x8 kl = *reinterpret_cast<const bf16x8*>(Kb + base);
  bf16x8 kh = *reinterpret_cast<const bf16x8*>(Kb + base + 64);
  bf16x8 qlo, qho, klo, kho;
#pragma unroll
  for (int j = 0; j < 8; ++j) {
    float d   = (float)(c * 8 + j);
    float ang = (float)s * expf(d * -0.14391156511756683f);
    float sn, cs;
    __sincosf(ang, &sn, &cs);
    float a0 = bf2f((unsigned short)ql[j]), a1 = bf2f((unsigned short)qh[j]);
    qlo[j] = (short)f2bf((a0 * cs - a1 * sn) * QSCALE);
    qho[j] = (short)f2bf((a1 * cs + a0 * sn) * QSCALE);
    float b0 = bf2f((unsigned short)kl[j]), b1 = bf2f((unsigned short)kh[j]);
    klo[j] = (short)f2bf(b0 * cs - b1 * sn);
    kho[j] = (short)f2bf(b1 * cs + b0 * sn);
  }
  *reinterpret_cast<bf16x8*>(Qb + base)      = qlo;
  *reinterpret_cast<bf16x8*>(Qb + base + 64) = qho;
  *reinterpret_cast<bf16x8*>(Kb + base)      = klo;
  *reinterpret_cast<bf16x8*>(Kb + base + 64) = kho;
}

// ---------------- causal flash attention (v6, unchanged) ----------------
constexpr int QB  = 128;
constexpr int KVB = 64;
constexpr int NQT = SEQ / QB;

__global__ __launch_bounds__(512)
__attribute__((amdgpu_waves_per_eu(4, 4)))
void k_attn(const unsigned short* __restrict__ Q,
            const unsigned short* __restrict__ Kk,
            const unsigned short* __restrict__ Vt,
            unsigned short* __restrict__ O) {
  __shared__ char lds[2 * 16384 + 2 * 16384 + 16384];
  char* Ks = lds;
  char* Vs = lds + 2 * 16384;
  char* Ps = lds + 4 * 16384;

  const int t    = threadIdx.x;
  const int lane = t & 63;
  const int w    = t >> 6;
  const int l15  = lane & 15, lg = lane >> 4;
  const int bh   = blockIdx.y;
  const int b    = bh >> 4, h = bh & 15;
  const int qt   = (bh >= HEADS) ? (NQT - 1 - (int)blockIdx.x) : (int)blockIdx.x;
  const int q0b  = qt * QB;
  const int q0w  = q0b + w * 16;
  const int qw_hi = q0w + 15;

  const unsigned short* Qb = Q  + (size_t)bh * SEQ * HD;
  const unsigned short* Kb = Kk + (size_t)bh * SEQ * HD;
  const unsigned short* Vb = Vt + (size_t)bh * HD * SEQ;

  bf16x8 qf[4];
#pragma unroll
  for (int c = 0; c < 4; ++c)
    qf[c] = *reinterpret_cast<const bf16x8*>(Qb + (size_t)(q0w + l15) * HD + c * 32 + lg * 8);

  float mrow[4], lpart[4];
  f32x4 oacc[8];
#pragma unroll
  for (int r = 0; r < 4; ++r) { mrow[r] = -1e30f; lpart[r] = 0.f; }
#pragma unroll
  for (int dt = 0; dt < 8; ++dt)
#pragma unroll
    for (int r = 0; r < 4; ++r) oacc[dt][r] = 0.f;

  const int sp     = t * 16;
  const int srow   = sp >> 8;
  const int scolb  = (sp & 255) ^ ((srow & 7) << 4);
  const unsigned short* ksrc2 = Kb + (size_t)srow * HD + (scolb >> 1);
  char* kdst2 = Ks + sp;

  const int vrow  = t >> 3;
  const int vcolb = ((t & 7) << 4) ^ ((vrow & 7) << 4);
  const unsigned short* vsrc = Vb + (size_t)vrow * SEQ + (vcolb >> 1);
  char* vdst = Vs + t * 16;

  const int nb = q0b / KVB + 2;

  gload_lds16(ksrc2, kdst2);
  gload_lds16(ksrc2 + (size_t)32 * HD, kdst2 + 8192);
  gload_lds16(vsrc, vdst);
  gload_lds16(vsrc + (size_t)64 * SEQ, vdst + 8192);
  __syncthreads();

  int cur = 0;
  for (int kb = 0; kb < nb; ++kb) {
    const int kv0 = kb * KVB;
    if (kb + 1 < nb) {
      const int nxt = kv0 + KVB;
      char* nk = kdst2 + (cur ^ 1) * 16384;
      char* nv = vdst  + (cur ^ 1) * 16384;
      gload_lds16(ksrc2 + (size_t)nxt * HD, nk);
      gload_lds16(ksrc2 + (size_t)(nxt + 32) * HD, nk + 8192);
      gload_lds16(vsrc + nxt, nv);
      gload_lds16(vsrc + (size_t)64 * SEQ + nxt, nv + 8192);
    }

    if (kv0 <= qw_hi) {
      const char* Kc = Ks + cur * 16384;
      const char* Vc = Vs + cur * 16384;
      f32x4 sc[4];
#pragma unroll
      for (int tt = 0; tt < 4; ++tt)
#pragma unroll
        for (int r = 0; r < 4; ++r) sc[tt][r] = 0.f;
      __builtin_amdgcn_s_setprio(1);
#pragma unroll
      for (int tt = 0; tt < 4; ++tt) {
        const int kr = tt * 16 + l15;
        const int xr = (kr & 7) << 4;
#pragma unroll
        for (int c = 0; c < 4; ++c) {
          bf16x8 kf = *reinterpret_cast<const bf16x8*>(
              Kc + kr * 256 + ((c * 64 + lg * 16) ^ xr));
          sc[tt] = __builtin_amdgcn_mfma_f32_16x16x32_bf16(qf[c], kf, sc[tt], 0, 0, 0);
        }
      }
      __builtin_amdgcn_s_setprio(0);

      const bool full = (kv0 + KVB - 1 <= q0w);
#pragma unroll
      for (int r = 0; r < 4; ++r) {
        const int qg = q0w + lg * 4 + r;
        float v0 = sc[0][r], v1 = sc[1][r];
        float v2 = sc[2][r], v3 = sc[3][r];
        if (!full) {
          if (kv0 +      l15 > qg) v0 = -1e30f;
          if (kv0 + 16 + l15 > qg) v1 = -1e30f;
          if (kv0 + 32 + l15 > qg) v2 = -1e30f;
          if (kv0 + 48 + l15 > qg) v3 = -1e30f;
        }
        float pm = fmaxf(fmaxf(v0, v1), fmaxf(v2, v3));
        if (__any(pm > mrow[r] + 11.5f)) {
          float pmr = pm;
          pmr = fmaxf(pmr, __shfl_xor(pmr, 1));
          pmr = fmaxf(pmr, __shfl_xor(pmr, 2));
          pmr = fmaxf(pmr, __shfl_xor(pmr, 4));
          pmr = fmaxf(pmr, __shfl_xor(pmr, 8));
          float mn = fmaxf(mrow[r], pmr);
          float al = exp2f(mrow[r] - mn);
          lpart[r] *= al;
#pragma unroll
          for (int dt = 0; dt < 8; ++dt) oacc[dt][r] *= al;
          mrow[r] = mn;
        }
        float p0 = exp2f(v0 - mrow[r]);
        float p1 = exp2f(v1 - mrow[r]);
        float p2 = exp2f(v2 - mrow[r]);
        float p3 = exp2f(v3 - mrow[r]);
        lpart[r] += (p0 + p1) + (p2 + p3);
        const int prow = lg * 4 + r;
        const int xpr  = (prow & 7) << 4;
        char* pw = Ps + w * 2048 + prow * 128;
        *reinterpret_cast<unsigned short*>(pw + (((0 * 32) + l15 * 2) ^ xpr)) = f2bft(p0);
        *reinterpret_cast<unsigned short*>(pw + (((1 * 32) + l15 * 2) ^ xpr)) = f2bft(p1);
        *reinterpret_cast<unsigned short*>(pw + (((2 * 32) + l15 * 2) ^ xpr)) = f2bft(p2);
        *reinterpret_cast<unsigned short*>(pw + (((3 * 32) + l15 * 2) ^ xpr)) = f2bft(p3);
      }
      asm volatile("s_waitcnt lgkmcnt(0)" ::: "memory");

      const int xq = (l15 & 7) << 4;
      const char* pr = Ps + w * 2048 + l15 * 128;
      bf16x8 pa0 = *reinterpret_cast<const bf16x8*>(pr + ((0  + lg * 16) ^ xq));
      bf16x8 pa1 = *reinterpret_cast<const bf16x8*>(pr + ((64 + lg * 16) ^ xq));
      const int xv = (l15 & 7) << 4;
      __builtin_amdgcn_s_setprio(1);
#pragma unroll
      for (int dt = 0; dt < 8; ++dt) {
        const char* vrl = Vc + (dt * 16 + l15) * 128;
        bf16x8 vf0 = *reinterpret_cast<const bf16x8*>(vrl + ((lg * 16) ^ xv));
        bf16x8 vf1 = *reinterpret_cast<const bf16x8*>(vrl + ((64 + lg * 16) ^ xv));
        oacc[dt] = __builtin_amdgcn_mfma_f32_16x16x32_bf16(pa0, vf0, oacc[dt], 0, 0, 0);
        oacc[dt] = __builtin_amdgcn_mfma_f32_16x16x32_bf16(pa1, vf1, oacc[dt], 0, 0, 0);
      }
      __builtin_amdgcn_s_setprio(0);
    }
    __syncthreads();
    cur ^= 1;
  }

  float inv[4];
#pragma unroll
  for (int r = 0; r < 4; ++r) {
    float ls = lpart[r];
    ls += __shfl_xor(ls, 1);
    ls += __shfl_xor(ls, 2);
    ls += __shfl_xor(ls, 4);
    ls += __shfl_xor(ls, 8);
    inv[r] = 1.0f / ls;
  }
#pragma unroll
  for (int dt = 0; dt < 8; ++dt) {
#pragma unroll
    for (int r = 0; r < 4; ++r) {
      int qg = q0w + lg * 4 + r;
      int dv = dt * 16 + l15;
      O[((size_t)(b * SEQ + qg) * HEADS + h) * HD + dv] = f2bf(oacc[dt][r] * inv[r]);
    }
  }
}

// ---------------- launch ----------------
extern "C" void kernel_launch(void* const* d_in, const int* in_sizes, int n_in,
                              void* d_out, int out_size, void* d_ws, size_t ws_size,
                              hipStream_t stream) {
  (void)in_sizes; (void)n_in; (void)out_size; (void)ws_size;
  const float* x  = (const float*)d_in[0];
  const float* Wq = (const float*)d_in[1];
  const float* Wk = (const float*)d_in[2];
  const float* Wv = (const float*)d_in[3];
  const float* Wo = (const float*)d_in[4];
  float* out = (float*)d_out;

  unsigned short* xb  = (unsigned short*)d_ws;
  unsigned short* wqb = xb  + (size_t)MROWS * HIDDEN;
  unsigned short* wkb = wqb + (size_t)HIDDEN * HIDDEN;
  unsigned short* wvb = wkb + (size_t)HIDDEN * HIDDEN;
  unsigned short* wob = wvb + (size_t)HIDDEN * HIDDEN;
  unsigned short* Qb  = wob + (size_t)HIDDEN * HIDDEN;
  unsigned short* Kb  = Qb  + (size_t)MROWS * HIDDEN;
  unsigned short* Vtb = Kb  + (size_t)MROWS * HIDDEN;
  unsigned short* Ob  = Vtb + (size_t)MROWS * HIDDEN;
  (void)wkb;

  // single conversion launch: x + 4 weights (dest contiguous from xb)
  constexpr int CVT_THREADS = (MROWS * HIDDEN + 4 * HIDDEN * HIDDEN) / 4;
  k_cvt_all<<<CVT_THREADS / 256, 256, 0, stream>>>(x, Wq, Wk, Wv, Wo, xb);

  // fused Q+K projection: 256x256 pipelined, 256 blocks
  k_gemm256<0, 256, 256><<<256, 512, 0, stream>>>(xb, wqb, Qb);
  // V^T projection: 128x256 pipelined (A=Wv, B=x), 256 blocks
  k_gemm256<3, 128, 256><<<256, 512, 0, stream>>>(wvb, xb, Vtb);

  k_rope<<<(BATCH * HEADS * SEQ * 8) / 256, 256, 0, stream>>>(Qb, Kb);

  k_attn<<<dim3(SEQ / QB, BATCH * HEADS), 512, 0, stream>>>(Qb, Kb, Vtb, Ob);

  // output projection: 256x128 pipelined, 256 blocks
  k_gemm256<2, 256, 128><<<256, 512, 0, stream>>>(Ob, wob, out);
}